// Round 2
// baseline (5259.206 us; speedup 1.0000x reference)
//
#include <hip/hip_runtime.h>
#include <hip/hip_bf16.h>

typedef unsigned int u32;
typedef unsigned short u16;
typedef __bf16 bf16_t;
typedef bf16_t bf16x8 __attribute__((ext_vector_type(8)));
typedef float f32x4 __attribute__((ext_vector_type(4)));

constexpr int NN = 50000;
constexpr int EE = 500000;
constexpr int RR = 8;

__device__ __forceinline__ float bf2f(u32 v){
  union { u32 u; float f; } x; x.u = (v & 0xFFFFu) << 16; return x.f;
}
__device__ __forceinline__ u16 f2bf(float f){
  union { u32 u; float f; } x; x.f = f;
  u32 r = x.u + 0x7FFFu + ((x.u >> 16) & 1u);
  return (u16)(r >> 16);
}
__device__ __forceinline__ float lrelu(float x){ return x > 0.f ? x : 0.1f * x; }
// mode-aware float load: fm=1 -> f32 source, fm=0 -> bf16 source
__device__ __forceinline__ float ldf(const void* p, int i, u32 fm){
  return fm ? ((const float*)p)[i] : bf2f(((const u16*)p)[i]);
}

// ---------------- dtype detectors ----------------
// float mode: scan x as u16; true-bf16 N(0,1) never has exponent>=0xFD,
// f32 mantissa halves hit it ~1.2% of the time.
__global__ void k_fdetect(const void* x, u32* md){
  __shared__ u32 c;
  if (threadIdx.x == 0) c = 0;
  __syncthreads();
  const u16* p = (const u16*)x;
  u32 loc = 0;
  for (int j = 0; j < 16; j++){
    u16 v = p[threadIdx.x * 16 + j];
    u32 e = (v >> 7) & 0xFF;
    if (e >= 0xFD) loc++;
  }
  atomicAdd(&c, loc);
  __syncthreads();
  if (threadIdx.x == 0) md[0] = (c >= 4) ? 1u : 0u;
}
// int mode: int64 => all odd int32 positions of edge_type are 0
__global__ void k_idetect(const void* et, u32* md){
  __shared__ u32 c;
  if (threadIdx.x == 0) c = 0;
  __syncthreads();
  const int* p = (const int*)et;
  u32 loc = 0;
  for (int j = 0; j < 8; j++){
    int idx = 2 * (threadIdx.x * 8 + j) + 1;
    if (p[idx] != 0) loc++;
  }
  atomicAdd(&c, loc);
  __syncthreads();
  if (threadIdx.x == 0) md[1] = (c == 0) ? 1u : 0u;
}

// ---------------- int conversion -> int32 ws copies
__global__ void k_icvt(const void* ei, const void* et, const void* bat,
                       int* ei_c, int* et_c, int* bat_c, const u32* md){
  u32 im = md[1];
  int i = blockIdx.x * 256 + threadIdx.x;
  if (i < 2 * EE){
    const int* p = (const int*)ei;
    ei_c[i] = im ? p[2 * i] : p[i];
  } else if (i < 3 * EE){
    int j = i - 2 * EE;
    const int* p = (const int*)et;
    et_c[j] = im ? p[2 * j] : p[j];
  } else if (i < 3 * EE + NN){
    int j = i - 3 * EE;
    const int* p = (const int*)bat;
    bat_c[j] = im ? p[2 * j] : p[j];
  }
}

// ---------------- x conversion -> bf16 ws copy (+NaN flag bit1)
__global__ void k_xcvt(const void* x, u16* xb, const u32* md, u32* flags){
  u32 fm = md[0];
  int i4 = (blockIdx.x * 256 + threadIdx.x) * 4;
  if (i4 >= NN * 128) return;
  float v[4];
  if (fm){
    float4 f = *(const float4*)((const float*)x + i4);
    v[0]=f.x; v[1]=f.y; v[2]=f.z; v[3]=f.w;
  } else {
    uint2 u = *(const uint2*)((const u16*)x + i4);
    v[0]=bf2f(u.x); v[1]=bf2f(u.x>>16); v[2]=bf2f(u.y); v[3]=bf2f(u.y>>16);
  }
  bool bad = false;
  u16 o[4];
  for (int j = 0; j < 4; j++){
    if (v[j] != v[j]){ bad = true; v[j] = 0.f; }
    o[j] = f2bf(v[j]);
  }
  unsigned long long bal = __ballot(bad);
  if (bal && (threadIdx.x & 63) == 0) atomicOr(flags, 2u);
  uint2 st;
  st.x = (u32)o[0] | ((u32)o[1] << 16);
  st.y = (u32)o[2] | ((u32)o[3] << 16);
  *(uint2*)(xb + i4) = st;
}

// ---------------- weight transpose: wcatT[L][n][k]; k<1024 -> W[L][k][n], else root[k-1024][n]
__global__ void k_wcat(const void* W1, const void* r1, const void* W2, const void* r2,
                       const void* W3, const void* r3, u16* wcatT, const u32* md, u32* flags){
  u32 fm = md[0];
  int idx = blockIdx.x * 256 + threadIdx.x;
  if (idx >= 3 * 128 * 1152) return;
  int L = idx / (128 * 1152);
  int rem = idx % (128 * 1152);
  int n = rem / 1152, k = rem % 1152;
  const void* W  = (L == 0) ? W1 : ((L == 1) ? W2 : W3);
  const void* rt = (L == 0) ? r1 : ((L == 1) ? r2 : r3);
  float v = (k < 1024) ? ldf(W, k * 128 + n, fm) : ldf(rt, (k - 1024) * 128 + n, fm);
  if (v != v){ v = 0.f; atomicOr(flags, 2u); }
  wcatT[idx] = f2bf(v);
}

// ---------------- edge sort machinery
__global__ void k_count(const int* ei, const int* et, u32* hist, u32* cnt){
  int e = blockIdx.x * 256 + threadIdx.x;
  if (e >= EE) return;
  int r = et[e];
  int dst = ei[EE + e];
  atomicAdd(&hist[r], 1u);
  atomicAdd(&cnt[dst * RR + r], 1u);
}
__global__ void k_prefix(const u32* hist, u32* relOff, u32* cursor){
  if (threadIdx.x == 0){
    u32 s = 0;
    for (int r = 0; r < RR; r++){ relOff[r] = s; cursor[r] = s; s += hist[r]; }
    relOff[RR] = s;
  }
}
__global__ void k_rcnt(const u32* cnt, float* rcnt){
  int i = blockIdx.x * 256 + threadIdx.x;
  if (i < NN * RR) rcnt[i] = 1.0f / (float)max(cnt[i], 1u);
}
__global__ void k_sort(const int* ei, const int* et, u32* cursor, u32* src_s, u32* dst_s){
  int e = blockIdx.x * 256 + threadIdx.x;
  if (e >= EE) return;
  int r = et[e];
  u32 p = atomicAdd(&cursor[r], 1u);
  src_s[p] = (u32)ei[e];
  dst_s[p] = (u32)ei[EE + e];
}

// ---------------- root GEMM: out[N,128] = h@root + bias (plain stores)
#define PADE 8
__global__ __launch_bounds__(256) void k_gemm_root(const u16* __restrict__ h,
                                                   const u16* __restrict__ wT,
                                                   const void* __restrict__ bias,
                                                   float* __restrict__ out, const u32* md){
  __shared__ u16 As[128][64 + PADE];
  __shared__ u16 Bs[128][64 + PADE];
  u32 fm = md[0];
  int m0 = blockIdx.x * 128;
  int tid = threadIdx.x;
  int w = tid >> 6, lane = tid & 63, qd = lane >> 4, l16 = lane & 15;
  f32x4 acc[2][8];
  for (int i = 0; i < 2; i++) for (int j = 0; j < 8; j++) acc[i][j] = (f32x4){0.f,0.f,0.f,0.f};
  for (int k0 = 0; k0 < 128; k0 += 64){
    __syncthreads();
    for (int it = 0; it < 4; it++){
      int lin = it * 2048 + tid * 8;
      int row = lin >> 6, kl = lin & 63;
      int node = m0 + row;
      uint4 v = make_uint4(0u,0u,0u,0u);
      if (node < NN) v = *(const uint4*)(h + node * 128 + k0 + kl);
      *(uint4*)(&As[row][kl]) = v;
      uint4 b = *(const uint4*)(wT + row * 1152 + 1024 + k0 + kl);
      *(uint4*)(&Bs[row][kl]) = b;
    }
    __syncthreads();
    for (int kk = 0; kk < 64; kk += 32){
      bf16x8 a[2], bf[8];
      for (int rt = 0; rt < 2; rt++) a[rt] = *(const bf16x8*)(&As[w * 32 + rt * 16 + l16][kk + qd * 8]);
      for (int ct = 0; ct < 8; ct++) bf[ct] = *(const bf16x8*)(&Bs[ct * 16 + l16][kk + qd * 8]);
      for (int rt = 0; rt < 2; rt++)
        for (int ct = 0; ct < 8; ct++)
          acc[rt][ct] = __builtin_amdgcn_mfma_f32_16x16x32_bf16(a[rt], bf[ct], acc[rt][ct], 0, 0, 0);
    }
  }
  for (int rt = 0; rt < 2; rt++){
    int rbase = m0 + w * 32 + rt * 16 + qd * 4;
    for (int ct = 0; ct < 8; ct++){
      int col = ct * 16 + l16;
      float bv = ldf(bias, col, fm);
      for (int rg = 0; rg < 4; rg++){
        int node = rbase + rg;
        if (node < NN) out[node * 128 + col] = acc[rt][ct][rg] + bv;
      }
    }
  }
}

// ---------------- edge kernel: out[dst] += (h[src] @ W[r]) * rcnt[dst,r]
__global__ __launch_bounds__(256) void k_edge(const u16* __restrict__ h,
                                              const u16* __restrict__ wT,
                                              const u32* __restrict__ src_s,
                                              const u32* __restrict__ dst_s,
                                              const u32* __restrict__ relOff,
                                              const float* __restrict__ rcnt,
                                              float* __restrict__ out){
  __shared__ u16 Ws[128][128 + PADE];
  __shared__ u16 As[32][128 + PADE];
  __shared__ float scL[32];
  __shared__ u32 dstL[32];
  int r = blockIdx.y;
  int tid = threadIdx.x;
  int w = tid >> 6, lane = tid & 63, qd = lane >> 4, l16 = lane & 15;
  for (int it = 0; it < 8; it++){
    int lin = it * 2048 + tid * 8;
    int n = lin >> 7, kl = lin & 127;
    *(uint4*)(&Ws[n][kl]) = *(const uint4*)(wT + n * 1152 + r * 128 + kl);
  }
  u32 start = relOff[r], end = relOff[r + 1];
  int ntiles = (int)(end - start + 31) >> 5;
  int mt = w & 1, nb = (w >> 1) * 4;
  for (int t = blockIdx.x; t < ntiles; t += gridDim.x){
    u32 e0 = start + ((u32)t << 5);
    int mvalid = min(32, (int)(end - e0));
    __syncthreads();
    {
      int row = tid >> 3, seg = tid & 7;
      uint4 v0 = make_uint4(0u,0u,0u,0u), v1 = v0;
      if (row < mvalid){
        u32 src = src_s[e0 + row];
        const u16* p = h + src * 128 + seg * 16;
        v0 = *(const uint4*)(p);
        v1 = *(const uint4*)(p + 8);
      }
      *(uint4*)(&As[row][seg * 16]) = v0;
      *(uint4*)(&As[row][seg * 16 + 8]) = v1;
      if (tid < 32){
        if (tid < mvalid){
          u32 d = dst_s[e0 + tid];
          dstL[tid] = d;
          scL[tid] = rcnt[d * RR + r];
        } else { dstL[tid] = 0; scL[tid] = 0.f; }
      }
    }
    __syncthreads();
    f32x4 acc[4];
    for (int i = 0; i < 4; i++) acc[i] = (f32x4){0.f,0.f,0.f,0.f};
    for (int kk = 0; kk < 128; kk += 32){
      bf16x8 a = *(const bf16x8*)(&As[mt * 16 + l16][kk + qd * 8]);
      for (int i = 0; i < 4; i++){
        bf16x8 b = *(const bf16x8*)(&Ws[(nb + i) * 16 + l16][kk + qd * 8]);
        acc[i] = __builtin_amdgcn_mfma_f32_16x16x32_bf16(a, b, acc[i], 0, 0, 0);
      }
    }
    for (int i = 0; i < 4; i++){
      int col = (nb + i) * 16 + l16;
      for (int rg = 0; rg < 4; rg++){
        int er = mt * 16 + qd * 4 + rg;
        if (er < mvalid)
          unsafeAtomicAdd(&out[dstL[er] * 128 + col], acc[i][rg] * scL[er]);
      }
    }
  }
}

// ---------------- BatchNorm
__global__ void k_bnstats(const float* __restrict__ out, float* __restrict__ stats){
  __shared__ float sb[256], sb2[256];
  int tid = threadIdx.x;
  int col = tid & 127, half = tid >> 7;
  int r0 = blockIdx.x * 256;
  float s = 0.f, s2 = 0.f;
  for (int i = half; i < 256; i += 2){
    int n = r0 + i;
    if (n < NN){ float v = out[n * 128 + col]; s += v; s2 += v * v; }
  }
  sb[tid] = s; sb2[tid] = s2;
  __syncthreads();
  if (half == 0){
    unsafeAtomicAdd(&stats[col],       sb[col] + sb[col + 128]);
    unsafeAtomicAdd(&stats[128 + col], sb2[col] + sb2[col + 128]);
  }
}

__global__ void k_bnapply(const float* __restrict__ out, const float* __restrict__ stats,
                          const void* __restrict__ g, const void* __restrict__ beta,
                          u16* __restrict__ hout, const u32* md, u32* flags, u32 layerbit){
  u32 fm = md[0];
  int idx = (blockIdx.x * 256 + threadIdx.x) * 4;
  if (idx >= NN * 128) return;
  int col = idx & 127;
  float4 v = *(const float4*)(out + idx);
  float vv[4] = {v.x, v.y, v.z, v.w};
  bool bad = false;
  u16 o[4];
  for (int j = 0; j < 4; j++){
    int c = col + j;
    float mu = stats[c] * (1.0f / NN);
    float var = fmaxf(stats[128 + c] * (1.0f / NN) - mu * mu, 0.f);
    float sc = ldf(g, c, fm) * rsqrtf(var + 1e-5f);
    float sh = ldf(beta, c, fm) - mu * sc;
    float r = vv[j] * sc + sh;
    if (r != r || sc != sc){ bad = true; r = 0.f; }
    o[j] = f2bf(lrelu(r));
  }
  unsigned long long bal = __ballot(bad);
  if (bal && (threadIdx.x & 63) == 0) atomicOr(flags, layerbit);
  uint2 st;
  st.x = (u32)o[0] | ((u32)o[1] << 16);
  st.y = (u32)o[2] | ((u32)o[3] << 16);
  *(uint2*)(hout + idx) = st;
}

// ---------------- attention scores: wave per node
__global__ __launch_bounds__(256) void k_scores(const float* __restrict__ emb,
                                                const void* A1, const void* a1,
                                                const void* A2, const void* a2,
                                                float* __restrict__ scores,
                                                const u32* md, u32* flags){
  __shared__ float er[4][128];
  u32 fm = md[0];
  int w = threadIdx.x >> 6, lane = threadIdx.x & 63;
  int n = blockIdx.x * 4 + w;
  float2 v = *(const float2*)(emb + n * 128 + lane * 2);
  bool bad = false;
  if (v.x != v.x){ bad = true; v.x = 0.f; }
  if (v.y != v.y){ bad = true; v.y = 0.f; }
  unsigned long long bal = __ballot(bad);
  if (bal && lane == 0) atomicOr(flags, 16u);
  er[w][lane * 2] = v.x; er[w][lane * 2 + 1] = v.y;
  __syncthreads();
  float hval = ldf(a1, lane, fm);
  for (int k = 0; k < 128; k++) hval += er[w][k] * ldf(A1, k * 64 + lane, fm);
  hval = lrelu(hval);
  float p = hval * ldf(A2, lane, fm);
  for (int off = 32; off; off >>= 1) p += __shfl_down(p, off);
  if (lane == 0) scores[n] = p + ldf(a2, 0, fm);
}

__device__ __forceinline__ u32 fmap(float f){
  union{u32 u; float f;} x; x.f = f;
  return (x.u & 0x80000000u) ? ~x.u : (x.u | 0x80000000u);
}
__device__ __forceinline__ float funmap(u32 m){
  union{u32 u; float f;} x;
  x.u = (m & 0x80000000u) ? (m ^ 0x80000000u) : ~m;
  return x.f;
}

__global__ void k_max(const float* __restrict__ scores, u32* smax){
  int gid = blockIdx.x * 256 + threadIdx.x;
  float m = -1e30f;
  for (int i = gid; i < NN; i += 256 * 128) m = fmaxf(m, scores[i]);
  for (int off = 32; off; off >>= 1) m = fmaxf(m, __shfl_down(m, off));
  if ((threadIdx.x & 63) == 0) atomicMax(smax, fmap(m));
}

__global__ void k_expsum(const float* __restrict__ scores, const u32* smax,
                         float* __restrict__ attnw, float* ssum, u32* flags){
  float mx = funmap(*smax);
  int gid = blockIdx.x * 256 + threadIdx.x;
  if (mx != mx){ if (gid == 0) atomicOr(flags, 32u); mx = 0.f; }
  float s = 0.f;
  bool bad = false;
  for (int i = gid; i < NN; i += 256 * 128){
    float e = __expf(scores[i] - mx);
    if (e != e){ bad = true; e = 0.f; }
    attnw[i] = e; s += e;
  }
  unsigned long long bal = __ballot(bad);
  if (bal && (threadIdx.x & 63) == 0) atomicOr(flags, 32u);
  for (int off = 32; off; off >>= 1) s += __shfl_down(s, off);
  if ((threadIdx.x & 63) == 0) unsafeAtomicAdd(ssum, s);
}

// ---------------- pooling: batch sorted; running per-graph accumulation
__global__ __launch_bounds__(128) void k_pool(const float* __restrict__ emb,
                                              const float* __restrict__ attnw,
                                              const float* __restrict__ ssum,
                                              const int* __restrict__ batch,
                                              float* __restrict__ gemb, u32* flags){
  int t = threadIdx.x;
  int n0 = blockIdx.x * 512;
  if (n0 >= NN) return;
  int n1 = min(n0 + 512, NN);
  float sv = *ssum;
  bool bad = !(sv > 0.f) || (sv != sv);
  if (bad && t == 0 && blockIdx.x == 0) atomicOr(flags, 64u);
  float rs = bad ? 0.f : 1.0f / sv;
  int cur = batch[n0];
  float acc = 0.f;
  for (int n = n0; n < n1; n++){
    int b = batch[n];
    if (b != cur){ unsafeAtomicAdd(&gemb[cur * 128 + t], acc * rs); acc = 0.f; cur = b; }
    acc += emb[n * 128 + t] * attnw[n];
  }
  unsafeAtomicAdd(&gemb[cur * 128 + t], acc * rs);
}

// ---------------- final combiner + row L2 normalize: wave per node
__global__ __launch_bounds__(256) void k_final(const float* __restrict__ emb,
                                               const float* __restrict__ gemb,
                                               const int* __restrict__ batch,
                                               const void* C1, const void* c1,
                                               const void* C2, const void* c2,
                                               void* __restrict__ outp,
                                               const u32* md, u32* flags){
  __shared__ float comb[4][256];
  __shared__ float hid[4][130];
  u32 fm = md[0];
  int w = threadIdx.x >> 6, lane = threadIdx.x & 63;
  int n = blockIdx.x * 4 + w;
  int g = batch[n];
  {
    float4 v;
    float* dst;
    if (lane < 32){ v = *(const float4*)(emb + n * 128 + lane * 4); dst = &comb[w][lane * 4]; }
    else { int l = lane - 32; v = *(const float4*)(gemb + g * 128 + l * 4); dst = &comb[w][128 + l * 4]; }
    bool bad = false;
    float a[4] = {v.x, v.y, v.z, v.w};
    for (int j = 0; j < 4; j++) if (a[j] != a[j]){ bad = true; a[j] = 0.f; }
    unsigned long long bal = __ballot(bad);
    if (bal && lane == 0) atomicOr(flags, 128u);
    dst[0]=a[0]; dst[1]=a[1]; dst[2]=a[2]; dst[3]=a[3];
  }
  __syncthreads();
  float h0 = ldf(c1, lane, fm), h1 = ldf(c1, lane + 64, fm);
  for (int k = 0; k < 256; k++){
    float c = comb[w][k];
    h0 += c * ldf(C1, k * 128 + lane, fm);
    h1 += c * ldf(C1, k * 128 + lane + 64, fm);
  }
  hid[w][lane] = lrelu(h0); hid[w][lane + 64] = lrelu(h1);
  __syncthreads();
  float o0 = ldf(c2, lane, fm), o1 = ldf(c2, lane + 64, fm);
  for (int k = 0; k < 128; k++){
    float hv = hid[w][k];
    o0 += hv * ldf(C2, k * 128 + lane, fm);
    o1 += hv * ldf(C2, k * 128 + lane + 64, fm);
  }
  bool bad = false;
  if (o0 != o0){ bad = true; o0 = 0.f; }
  if (o1 != o1){ bad = true; o1 = 0.f; }
  unsigned long long bal = __ballot(bad);
  if (bal && lane == 0) atomicOr(flags, 256u);
  float ss = o0 * o0 + o1 * o1;
  for (int off = 32; off; off >>= 1) ss += __shfl_xor(ss, off);
  float sc = 1.0f / fmaxf(sqrtf(ss), 1e-12f);
  if (fm){
    float* op = (float*)outp;
    op[n * 128 + lane]      = o0 * sc;
    op[n * 128 + lane + 64] = o1 * sc;
  } else {
    u16* op = (u16*)outp;
    op[n * 128 + lane]      = f2bf(o0 * sc);
    op[n * 128 + lane + 64] = f2bf(o1 * sc);
  }
}

// ---------------- diag sentinels: only touches out if something is broken
__global__ void k_diag(const u32* relOff, const u32* flags, const u32* md, void* outp){
  if (threadIdx.x != 0 || blockIdx.x != 0) return;
  u32 fm = md[0];
  u32 f = flags[0];
  if (relOff[RR] != (u32)EE) f |= 1u;
  for (int b = 0; b < 9; b++){
    if (f & (1u << b)){
      float s = (float)(131072 >> b);
      if (fm) ((float*)outp)[b] = s;
      else ((u16*)outp)[b] = f2bf(s);
    }
  }
}
__global__ void k_wsfail(u32* outp){ outp[0] = 0x43000000u; } // 128.0f / [0,128.0bf16]

// ---------------- workspace layout (bytes)
constexpr size_t O_OUT   = 0;
constexpr size_t O_H     = 25600000;
constexpr size_t O_XBF   = 38400000;
constexpr size_t O_WCAT  = 51200000;
constexpr size_t O_EI    = 52084736;
constexpr size_t O_ET    = 56084736;
constexpr size_t O_BAT   = 58084736;
constexpr size_t O_SRC   = 58284736;
constexpr size_t O_DST   = 60284736;
constexpr size_t O_CNT   = 62284736;
constexpr size_t O_RCNT  = 63884736;
constexpr size_t O_SCO   = 65484736;
constexpr size_t O_AW    = 65684736;
constexpr size_t O_GEMB  = 65884736;
constexpr size_t O_STATS = 65917504;
constexpr size_t O_MISC  = 65919552;
constexpr size_t WS_NEED = 65919808;

extern "C" void kernel_launch(void* const* d_in, const int* in_sizes, int n_in,
                              void* d_out, int out_size, void* d_ws, size_t ws_size,
                              hipStream_t stream) {
  const void* x     = d_in[0];
  const void* ei    = d_in[1];
  const void* et    = d_in[2];
  const void* batch = d_in[3];
  const void* W1 = d_in[4],  *r1 = d_in[5],  *b1 = d_in[6];
  const void* W2 = d_in[7],  *r2 = d_in[8],  *b2 = d_in[9];
  const void* W3 = d_in[10], *r3 = d_in[11], *b3 = d_in[12];
  const void* g1 = d_in[13], *be1 = d_in[14];
  const void* g2 = d_in[15], *be2 = d_in[16];
  const void* A1 = d_in[17], *a1 = d_in[18];
  const void* A2 = d_in[19], *a2 = d_in[20];
  const void* C1 = d_in[21], *c1 = d_in[22];
  const void* C2 = d_in[23], *c2 = d_in[24];

  if (ws_size < WS_NEED){ k_wsfail<<<1, 1, 0, stream>>>((u32*)d_out); return; }
  char* ws = (char*)d_ws;
  float* out   = (float*)(ws + O_OUT);
  u16*   hbuf  = (u16*)(ws + O_H);
  u16*   xbf   = (u16*)(ws + O_XBF);
  u16*   wcat  = (u16*)(ws + O_WCAT);
  int*   ei_c  = (int*)(ws + O_EI);
  int*   et_c  = (int*)(ws + O_ET);
  int*   bat_c = (int*)(ws + O_BAT);
  u32*   src_s = (u32*)(ws + O_SRC);
  u32*   dst_s = (u32*)(ws + O_DST);
  u32*   cnt   = (u32*)(ws + O_CNT);
  float* rcnt  = (float*)(ws + O_RCNT);
  float* sco   = (float*)(ws + O_SCO);
  float* aw    = (float*)(ws + O_AW);
  float* gemb  = (float*)(ws + O_GEMB);
  float* stats = (float*)(ws + O_STATS);
  u32*   misc  = (u32*)(ws + O_MISC);
  u32* hist = misc;          // 0..7
  u32* cursor = misc + 8;    // 8..15
  u32* relOff = misc + 16;   // 16..24
  u32* smax = misc + 25;
  float* ssum = (float*)(misc + 26);
  u32* flags = misc + 27;
  u32* md = misc + 28;       // md[0]=fmode(f32?), md[1]=imode(int64?)

  hipMemsetAsync(ws + O_CNT, 0, 1600000, stream);
  hipMemsetAsync(ws + O_GEMB, 0, 32768 + 2048 + 256, stream);

  k_fdetect<<<1, 256, 0, stream>>>(x, md);
  k_idetect<<<1, 256, 0, stream>>>(et, md);
  k_icvt<<<6055, 256, 0, stream>>>(ei, et, batch, ei_c, et_c, bat_c, md);
  k_xcvt<<<6250, 256, 0, stream>>>(x, xbf, md, flags);
  k_wcat<<<1728, 256, 0, stream>>>(W1, r1, W2, r2, W3, r3, wcat, md, flags);

  k_count<<<(EE + 255) / 256, 256, 0, stream>>>(ei_c, et_c, hist, cnt);
  k_prefix<<<1, 64, 0, stream>>>(hist, relOff, cursor);
  k_rcnt<<<(NN * RR + 255) / 256, 256, 0, stream>>>(cnt, rcnt);
  k_sort<<<(EE + 255) / 256, 256, 0, stream>>>(ei_c, et_c, cursor, src_s, dst_s);

  const void* bias[3] = {b1, b2, b3};
  const void* gam[2] = {g1, g2};
  const void* bet[2] = {be1, be2};
  const u16* hin = xbf;
  for (int L = 0; L < 3; L++){
    const u16* wT = wcat + (size_t)L * 128 * 1152;
    k_gemm_root<<<391, 256, 0, stream>>>(hin, wT, bias[L], out, md);
    k_edge<<<dim3(96, 8), 256, 0, stream>>>(hin, wT, src_s, dst_s, relOff, rcnt, out);
    if (L < 2){
      k_bnstats<<<196, 256, 0, stream>>>(out, stats + L * 256);
      k_bnapply<<<6250, 256, 0, stream>>>(out, stats + L * 256, gam[L], bet[L], hbuf, md, flags, 4u << L);
      hin = hbuf;
    }
  }
  k_scores<<<12500, 256, 0, stream>>>(out, A1, a1, A2, a2, sco, md, flags);
  k_max<<<128, 256, 0, stream>>>(sco, smax);
  k_expsum<<<128, 256, 0, stream>>>(sco, smax, aw, ssum, flags);
  k_pool<<<98, 128, 0, stream>>>(out, aw, ssum, bat_c, gemb, flags);
  k_final<<<12500, 256, 0, stream>>>(out, gemb, bat_c, C1, c1, C2, c2, d_out, md, flags);
  k_diag<<<1, 64, 0, stream>>>(relOff, flags, md, d_out);
}

// Round 3
// 1692.241 us; speedup vs baseline: 3.1078x; 3.1078x over previous
//
#include <hip/hip_runtime.h>
#include <hip/hip_bf16.h>

typedef unsigned int u32;
typedef unsigned short u16;
typedef __bf16 bf16_t;
typedef bf16_t bf16x8 __attribute__((ext_vector_type(8)));
typedef float f32x4 __attribute__((ext_vector_type(4)));

constexpr int NN = 50000;
constexpr int EE = 500000;
constexpr int RR = 8;
constexpr int SORT_B = (EE + 255) / 256;   // 1954

__device__ __forceinline__ float bf2f(u32 v){
  union { u32 u; float f; } x; x.u = (v & 0xFFFFu) << 16; return x.f;
}
__device__ __forceinline__ u16 f2bf(float f){
  union { u32 u; float f; } x; x.f = f;
  u32 r = x.u + 0x7FFFu + ((x.u >> 16) & 1u);
  return (u16)(r >> 16);
}
__device__ __forceinline__ float lrelu(float x){ return x > 0.f ? x : 0.1f * x; }
// mode-aware float load: fm=1 -> f32 source, fm=0 -> bf16 source
__device__ __forceinline__ float ldf(const void* p, int i, u32 fm){
  return fm ? ((const float*)p)[i] : bf2f(((const u16*)p)[i]);
}

// ---------------- dtype detectors ----------------
__global__ void k_fdetect(const void* x, u32* md){
  __shared__ u32 c;
  if (threadIdx.x == 0) c = 0;
  __syncthreads();
  const u16* p = (const u16*)x;
  u32 loc = 0;
  for (int j = 0; j < 16; j++){
    u16 v = p[threadIdx.x * 16 + j];
    u32 e = (v >> 7) & 0xFF;
    if (e >= 0xFD) loc++;
  }
  atomicAdd(&c, loc);
  __syncthreads();
  if (threadIdx.x == 0) md[0] = (c >= 4) ? 1u : 0u;
}
__global__ void k_idetect(const void* et, u32* md){
  __shared__ u32 c;
  if (threadIdx.x == 0) c = 0;
  __syncthreads();
  const int* p = (const int*)et;
  u32 loc = 0;
  for (int j = 0; j < 8; j++){
    int idx = 2 * (threadIdx.x * 8 + j) + 1;
    if (p[idx] != 0) loc++;
  }
  atomicAdd(&c, loc);
  __syncthreads();
  if (threadIdx.x == 0) md[1] = (c == 0) ? 1u : 0u;
}

// ---------------- int conversion -> int32 ws copies
__global__ void k_icvt(const void* ei, const void* et, const void* bat,
                       int* ei_c, int* et_c, int* bat_c, const u32* md){
  u32 im = md[1];
  int i = blockIdx.x * 256 + threadIdx.x;
  if (i < 2 * EE){
    const int* p = (const int*)ei;
    ei_c[i] = im ? p[2 * i] : p[i];
  } else if (i < 3 * EE){
    int j = i - 2 * EE;
    const int* p = (const int*)et;
    et_c[j] = im ? p[2 * j] : p[j];
  } else if (i < 3 * EE + NN){
    int j = i - 3 * EE;
    const int* p = (const int*)bat;
    bat_c[j] = im ? p[2 * j] : p[j];
  }
}

// ---------------- x conversion -> bf16 ws copy (+NaN flag bit1)
__global__ void k_xcvt(const void* x, u16* xb, const u32* md, u32* flags){
  u32 fm = md[0];
  int i4 = (blockIdx.x * 256 + threadIdx.x) * 4;
  if (i4 >= NN * 128) return;
  float v[4];
  if (fm){
    float4 f = *(const float4*)((const float*)x + i4);
    v[0]=f.x; v[1]=f.y; v[2]=f.z; v[3]=f.w;
  } else {
    uint2 u = *(const uint2*)((const u16*)x + i4);
    v[0]=bf2f(u.x); v[1]=bf2f(u.x>>16); v[2]=bf2f(u.y); v[3]=bf2f(u.y>>16);
  }
  bool bad = false;
  u16 o[4];
  for (int j = 0; j < 4; j++){
    if (v[j] != v[j]){ bad = true; v[j] = 0.f; }
    o[j] = f2bf(v[j]);
  }
  unsigned long long bal = __ballot(bad);
  if (bal && (threadIdx.x & 63) == 0) atomicOr(flags, 2u);
  uint2 st;
  st.x = (u32)o[0] | ((u32)o[1] << 16);
  st.y = (u32)o[2] | ((u32)o[3] << 16);
  *(uint2*)(xb + i4) = st;
}

// ---------------- weight transpose: wcatT[L][n][k]; k<1024 -> W[L][k][n], else root[k-1024][n]
__global__ void k_wcat(const void* W1, const void* r1, const void* W2, const void* r2,
                       const void* W3, const void* r3, u16* wcatT, const u32* md, u32* flags){
  u32 fm = md[0];
  int idx = blockIdx.x * 256 + threadIdx.x;
  if (idx >= 3 * 128 * 1152) return;
  int L = idx / (128 * 1152);
  int rem = idx % (128 * 1152);
  int n = rem / 1152, k = rem % 1152;
  const void* W  = (L == 0) ? W1 : ((L == 1) ? W2 : W3);
  const void* rt = (L == 0) ? r1 : ((L == 1) ? r2 : r3);
  float v = (k < 1024) ? ldf(W, k * 128 + n, fm) : ldf(rt, (k - 1024) * 128 + n, fm);
  if (v != v){ v = 0.f; atomicOr(flags, 2u); }
  wcatT[idx] = f2bf(v);
}

// ---------------- contention-free relation sort ----------------
// phase 1: per-block relation histogram (LDS) + per-(dst,rel) degree (spread atomics)
__global__ void k_count2(const int* __restrict__ ei, const int* __restrict__ et,
                         u32* __restrict__ blockCnt, u32* __restrict__ cnt){
  __shared__ u32 lh[RR];
  if (threadIdx.x < RR) lh[threadIdx.x] = 0;
  __syncthreads();
  int e = blockIdx.x * 256 + threadIdx.x;
  if (e < EE){
    int r = et[e];
    int dst = ei[EE + e];
    atomicAdd(&cnt[dst * RR + r], 1u);
    atomicAdd(&lh[r], 1u);
  }
  __syncthreads();
  if (threadIdx.x < RR) blockCnt[blockIdx.x * RR + threadIdx.x] = lh[threadIdx.x];
}
// phase 2: one block; lane r scans its relation over all blocks
__global__ void k_scan(const u32* __restrict__ blockCnt, u32* __restrict__ blockOff,
                       u32* __restrict__ relTot, u32* __restrict__ relOff){
  int r = threadIdx.x;
  if (r < RR){
    u32 s = 0;
    for (int b = 0; b < SORT_B; b++){
      blockOff[b * RR + r] = s;
      s += blockCnt[b * RR + r];
    }
    relTot[r] = s;
  }
  __syncthreads();
  if (threadIdx.x == 0){
    u32 s = 0;
    for (int q = 0; q < RR; q++){ relOff[q] = s; s += relTot[q]; }
    relOff[RR] = s;
  }
}
// phase 3: scatter with block-local LDS ranking (no global contention)
__global__ void k_sort2(const int* __restrict__ ei, const int* __restrict__ et,
                        const u32* __restrict__ blockOff, const u32* __restrict__ relOff,
                        u32* __restrict__ src_s, u32* __restrict__ dst_s){
  __shared__ u32 lh[RR];
  __shared__ u32 base[RR];
  int tid = threadIdx.x;
  if (tid < RR){ lh[tid] = 0; base[tid] = relOff[tid] + blockOff[blockIdx.x * RR + tid]; }
  __syncthreads();
  int e = blockIdx.x * 256 + tid;
  if (e < EE){
    int r = et[e];
    u32 rank = atomicAdd(&lh[r], 1u);
    u32 p = base[r] + rank;
    src_s[p] = (u32)ei[e];
    dst_s[p] = (u32)ei[EE + e];
  }
}

__global__ void k_rcnt(const u32* cnt, float* rcnt){
  int i = blockIdx.x * 256 + threadIdx.x;
  if (i < NN * RR) rcnt[i] = 1.0f / (float)max(cnt[i], 1u);
}

// ---------------- root GEMM: out[N,128] = h@root + bias (plain stores)
#define PADE 8
__global__ __launch_bounds__(256) void k_gemm_root(const u16* __restrict__ h,
                                                   const u16* __restrict__ wT,
                                                   const void* __restrict__ bias,
                                                   float* __restrict__ out, const u32* md){
  __shared__ u16 As[128][64 + PADE];
  __shared__ u16 Bs[128][64 + PADE];
  u32 fm = md[0];
  int m0 = blockIdx.x * 128;
  int tid = threadIdx.x;
  int w = tid >> 6, lane = tid & 63, qd = lane >> 4, l16 = lane & 15;
  f32x4 acc[2][8];
  for (int i = 0; i < 2; i++) for (int j = 0; j < 8; j++) acc[i][j] = (f32x4){0.f,0.f,0.f,0.f};
  for (int k0 = 0; k0 < 128; k0 += 64){
    __syncthreads();
    for (int it = 0; it < 4; it++){
      int lin = it * 2048 + tid * 8;
      int row = lin >> 6, kl = lin & 63;
      int node = m0 + row;
      uint4 v = make_uint4(0u,0u,0u,0u);
      if (node < NN) v = *(const uint4*)(h + node * 128 + k0 + kl);
      *(uint4*)(&As[row][kl]) = v;
      uint4 b = *(const uint4*)(wT + row * 1152 + 1024 + k0 + kl);
      *(uint4*)(&Bs[row][kl]) = b;
    }
    __syncthreads();
    for (int kk = 0; kk < 64; kk += 32){
      bf16x8 a[2], bf[8];
      for (int rt = 0; rt < 2; rt++) a[rt] = *(const bf16x8*)(&As[w * 32 + rt * 16 + l16][kk + qd * 8]);
      for (int ct = 0; ct < 8; ct++) bf[ct] = *(const bf16x8*)(&Bs[ct * 16 + l16][kk + qd * 8]);
      for (int rt = 0; rt < 2; rt++)
        for (int ct = 0; ct < 8; ct++)
          acc[rt][ct] = __builtin_amdgcn_mfma_f32_16x16x32_bf16(a[rt], bf[ct], acc[rt][ct], 0, 0, 0);
    }
  }
  for (int rt = 0; rt < 2; rt++){
    int rbase = m0 + w * 32 + rt * 16 + qd * 4;
    for (int ct = 0; ct < 8; ct++){
      int col = ct * 16 + l16;
      float bv = ldf(bias, col, fm);
      for (int rg = 0; rg < 4; rg++){
        int node = rbase + rg;
        if (node < NN) out[node * 128 + col] = acc[rt][ct][rg] + bv;
      }
    }
  }
}

// ---------------- edge kernel: out[dst] += (h[src] @ W[r]) * rcnt[dst,r]
__global__ __launch_bounds__(256) void k_edge(const u16* __restrict__ h,
                                              const u16* __restrict__ wT,
                                              const u32* __restrict__ src_s,
                                              const u32* __restrict__ dst_s,
                                              const u32* __restrict__ relOff,
                                              const float* __restrict__ rcnt,
                                              float* __restrict__ out){
  __shared__ u16 Ws[128][128 + PADE];
  __shared__ u16 As[32][128 + PADE];
  __shared__ float scL[32];
  __shared__ u32 dstL[32];
  int r = blockIdx.y;
  int tid = threadIdx.x;
  int w = tid >> 6, lane = tid & 63, qd = lane >> 4, l16 = lane & 15;
  for (int it = 0; it < 8; it++){
    int lin = it * 2048 + tid * 8;
    int n = lin >> 7, kl = lin & 127;
    *(uint4*)(&Ws[n][kl]) = *(const uint4*)(wT + n * 1152 + r * 128 + kl);
  }
  u32 start = relOff[r], end = relOff[r + 1];
  int ntiles = (int)(end - start + 31) >> 5;
  int mt = w & 1, nb = (w >> 1) * 4;
  for (int t = blockIdx.x; t < ntiles; t += gridDim.x){
    u32 e0 = start + ((u32)t << 5);
    int mvalid = min(32, (int)(end - e0));
    __syncthreads();
    {
      int row = tid >> 3, seg = tid & 7;
      uint4 v0 = make_uint4(0u,0u,0u,0u), v1 = v0;
      if (row < mvalid){
        u32 src = src_s[e0 + row];
        const u16* p = h + src * 128 + seg * 16;
        v0 = *(const uint4*)(p);
        v1 = *(const uint4*)(p + 8);
      }
      *(uint4*)(&As[row][seg * 16]) = v0;
      *(uint4*)(&As[row][seg * 16 + 8]) = v1;
      if (tid < 32){
        if (tid < mvalid){
          u32 d = dst_s[e0 + tid];
          dstL[tid] = d;
          scL[tid] = rcnt[d * RR + r];
        } else { dstL[tid] = 0; scL[tid] = 0.f; }
      }
    }
    __syncthreads();
    f32x4 acc[4];
    for (int i = 0; i < 4; i++) acc[i] = (f32x4){0.f,0.f,0.f,0.f};
    for (int kk = 0; kk < 128; kk += 32){
      bf16x8 a = *(const bf16x8*)(&As[mt * 16 + l16][kk + qd * 8]);
      for (int i = 0; i < 4; i++){
        bf16x8 b = *(const bf16x8*)(&Ws[(nb + i) * 16 + l16][kk + qd * 8]);
        acc[i] = __builtin_amdgcn_mfma_f32_16x16x32_bf16(a, b, acc[i], 0, 0, 0);
      }
    }
    for (int i = 0; i < 4; i++){
      int col = (nb + i) * 16 + l16;
      for (int rg = 0; rg < 4; rg++){
        int er = mt * 16 + qd * 4 + rg;
        if (er < mvalid)
          unsafeAtomicAdd(&out[dstL[er] * 128 + col], acc[i][rg] * scL[er]);
      }
    }
  }
}

// ---------------- BatchNorm
__global__ void k_bnstats(const float* __restrict__ out, float* __restrict__ stats){
  __shared__ float sb[256], sb2[256];
  int tid = threadIdx.x;
  int col = tid & 127, half = tid >> 7;
  int r0 = blockIdx.x * 256;
  float s = 0.f, s2 = 0.f;
  for (int i = half; i < 256; i += 2){
    int n = r0 + i;
    if (n < NN){ float v = out[n * 128 + col]; s += v; s2 += v * v; }
  }
  sb[tid] = s; sb2[tid] = s2;
  __syncthreads();
  if (half == 0){
    unsafeAtomicAdd(&stats[col],       sb[col] + sb[col + 128]);
    unsafeAtomicAdd(&stats[128 + col], sb2[col] + sb2[col + 128]);
  }
}

__global__ void k_bnapply(const float* __restrict__ out, const float* __restrict__ stats,
                          const void* __restrict__ g, const void* __restrict__ beta,
                          u16* __restrict__ hout, const u32* md, u32* flags, u32 layerbit){
  u32 fm = md[0];
  int idx = (blockIdx.x * 256 + threadIdx.x) * 4;
  if (idx >= NN * 128) return;
  int col = idx & 127;
  float4 v = *(const float4*)(out + idx);
  float vv[4] = {v.x, v.y, v.z, v.w};
  bool bad = false;
  u16 o[4];
  for (int j = 0; j < 4; j++){
    int c = col + j;
    float mu = stats[c] * (1.0f / NN);
    float var = fmaxf(stats[128 + c] * (1.0f / NN) - mu * mu, 0.f);
    float sc = ldf(g, c, fm) * rsqrtf(var + 1e-5f);
    float sh = ldf(beta, c, fm) - mu * sc;
    float r = vv[j] * sc + sh;
    if (r != r || sc != sc){ bad = true; r = 0.f; }
    o[j] = f2bf(lrelu(r));
  }
  unsigned long long bal = __ballot(bad);
  if (bal && (threadIdx.x & 63) == 0) atomicOr(flags, layerbit);
  uint2 st;
  st.x = (u32)o[0] | ((u32)o[1] << 16);
  st.y = (u32)o[2] | ((u32)o[3] << 16);
  *(uint2*)(hout + idx) = st;
}

// ---------------- attention scores: wave per node
__global__ __launch_bounds__(256) void k_scores(const float* __restrict__ emb,
                                                const void* A1, const void* a1,
                                                const void* A2, const void* a2,
                                                float* __restrict__ scores,
                                                const u32* md, u32* flags){
  __shared__ float er[4][128];
  u32 fm = md[0];
  int w = threadIdx.x >> 6, lane = threadIdx.x & 63;
  int n = blockIdx.x * 4 + w;
  float2 v = *(const float2*)(emb + n * 128 + lane * 2);
  bool bad = false;
  if (v.x != v.x){ bad = true; v.x = 0.f; }
  if (v.y != v.y){ bad = true; v.y = 0.f; }
  unsigned long long bal = __ballot(bad);
  if (bal && lane == 0) atomicOr(flags, 16u);
  er[w][lane * 2] = v.x; er[w][lane * 2 + 1] = v.y;
  __syncthreads();
  float hval = ldf(a1, lane, fm);
  for (int k = 0; k < 128; k++) hval += er[w][k] * ldf(A1, k * 64 + lane, fm);
  hval = lrelu(hval);
  float p = hval * ldf(A2, lane, fm);
  for (int off = 32; off; off >>= 1) p += __shfl_down(p, off);
  if (lane == 0) scores[n] = p + ldf(a2, 0, fm);
}

__device__ __forceinline__ u32 fmap(float f){
  union{u32 u; float f;} x; x.f = f;
  return (x.u & 0x80000000u) ? ~x.u : (x.u | 0x80000000u);
}
__device__ __forceinline__ float funmap(u32 m){
  union{u32 u; float f;} x;
  x.u = (m & 0x80000000u) ? (m ^ 0x80000000u) : ~m;
  return x.f;
}

__global__ void k_max(const float* __restrict__ scores, u32* smax){
  int gid = blockIdx.x * 256 + threadIdx.x;
  float m = -1e30f;
  for (int i = gid; i < NN; i += 256 * 128) m = fmaxf(m, scores[i]);
  for (int off = 32; off; off >>= 1) m = fmaxf(m, __shfl_down(m, off));
  if ((threadIdx.x & 63) == 0) atomicMax(smax, fmap(m));
}

__global__ void k_expsum(const float* __restrict__ scores, const u32* smax,
                         float* __restrict__ attnw, float* ssum, u32* flags){
  float mx = funmap(*smax);
  int gid = blockIdx.x * 256 + threadIdx.x;
  if (mx != mx){ if (gid == 0) atomicOr(flags, 32u); mx = 0.f; }
  float s = 0.f;
  bool bad = false;
  for (int i = gid; i < NN; i += 256 * 128){
    float e = __expf(scores[i] - mx);
    if (e != e){ bad = true; e = 0.f; }
    attnw[i] = e; s += e;
  }
  unsigned long long bal = __ballot(bad);
  if (bal && (threadIdx.x & 63) == 0) atomicOr(flags, 32u);
  for (int off = 32; off; off >>= 1) s += __shfl_down(s, off);
  if ((threadIdx.x & 63) == 0) unsafeAtomicAdd(ssum, s);
}

// ---------------- pooling: batch sorted; running per-graph accumulation
__global__ __launch_bounds__(128) void k_pool(const float* __restrict__ emb,
                                              const float* __restrict__ attnw,
                                              const float* __restrict__ ssum,
                                              const int* __restrict__ batch,
                                              float* __restrict__ gemb, u32* flags){
  int t = threadIdx.x;
  int n0 = blockIdx.x * 512;
  if (n0 >= NN) return;
  int n1 = min(n0 + 512, NN);
  float sv = *ssum;
  bool bad = !(sv > 0.f) || (sv != sv);
  if (bad && t == 0 && blockIdx.x == 0) atomicOr(flags, 64u);
  float rs = bad ? 0.f : 1.0f / sv;
  int cur = batch[n0];
  float acc = 0.f;
  for (int n = n0; n < n1; n++){
    int b = batch[n];
    if (b != cur){ unsafeAtomicAdd(&gemb[cur * 128 + t], acc * rs); acc = 0.f; cur = b; }
    acc += emb[n * 128 + t] * attnw[n];
  }
  unsafeAtomicAdd(&gemb[cur * 128 + t], acc * rs);
}

// ---------------- final combiner + row L2 normalize: wave per node
__global__ __launch_bounds__(256) void k_final(const float* __restrict__ emb,
                                               const float* __restrict__ gemb,
                                               const int* __restrict__ batch,
                                               const void* C1, const void* c1,
                                               const void* C2, const void* c2,
                                               void* __restrict__ outp,
                                               const u32* md, u32* flags){
  __shared__ float comb[4][256];
  __shared__ float hid[4][130];
  u32 fm = md[0];
  int w = threadIdx.x >> 6, lane = threadIdx.x & 63;
  int n = blockIdx.x * 4 + w;
  int g = batch[n];
  {
    float4 v;
    float* dst;
    if (lane < 32){ v = *(const float4*)(emb + n * 128 + lane * 4); dst = &comb[w][lane * 4]; }
    else { int l = lane - 32; v = *(const float4*)(gemb + g * 128 + l * 4); dst = &comb[w][128 + l * 4]; }
    bool bad = false;
    float a[4] = {v.x, v.y, v.z, v.w};
    for (int j = 0; j < 4; j++) if (a[j] != a[j]){ bad = true; a[j] = 0.f; }
    unsigned long long bal = __ballot(bad);
    if (bal && lane == 0) atomicOr(flags, 128u);
    dst[0]=a[0]; dst[1]=a[1]; dst[2]=a[2]; dst[3]=a[3];
  }
  __syncthreads();
  float h0 = ldf(c1, lane, fm), h1 = ldf(c1, lane + 64, fm);
  for (int k = 0; k < 256; k++){
    float c = comb[w][k];
    h0 += c * ldf(C1, k * 128 + lane, fm);
    h1 += c * ldf(C1, k * 128 + lane + 64, fm);
  }
  hid[w][lane] = lrelu(h0); hid[w][lane + 64] = lrelu(h1);
  __syncthreads();
  float o0 = ldf(c2, lane, fm), o1 = ldf(c2, lane + 64, fm);
  for (int k = 0; k < 128; k++){
    float hv = hid[w][k];
    o0 += hv * ldf(C2, k * 128 + lane, fm);
    o1 += hv * ldf(C2, k * 128 + lane + 64, fm);
  }
  bool bad = false;
  if (o0 != o0){ bad = true; o0 = 0.f; }
  if (o1 != o1){ bad = true; o1 = 0.f; }
  unsigned long long bal = __ballot(bad);
  if (bal && lane == 0) atomicOr(flags, 256u);
  float ss = o0 * o0 + o1 * o1;
  for (int off = 32; off; off >>= 1) ss += __shfl_xor(ss, off);
  float sc = 1.0f / fmaxf(sqrtf(ss), 1e-12f);
  if (fm){
    float* op = (float*)outp;
    op[n * 128 + lane]      = o0 * sc;
    op[n * 128 + lane + 64] = o1 * sc;
  } else {
    u16* op = (u16*)outp;
    op[n * 128 + lane]      = f2bf(o0 * sc);
    op[n * 128 + lane + 64] = f2bf(o1 * sc);
  }
}

// ---------------- diag sentinels: only touches out if something is broken
__global__ void k_diag(const u32* relOff, const u32* flags, const u32* md, void* outp){
  if (threadIdx.x != 0 || blockIdx.x != 0) return;
  u32 fm = md[0];
  u32 f = flags[0];
  if (relOff[RR] != (u32)EE) f |= 1u;
  for (int b = 0; b < 9; b++){
    if (f & (1u << b)){
      float s = (float)(131072 >> b);
      if (fm) ((float*)outp)[b] = s;
      else ((u16*)outp)[b] = f2bf(s);
    }
  }
}
__global__ void k_wsfail(u32* outp){ outp[0] = 0x43000000u; }

// ---------------- workspace layout (bytes)
constexpr size_t O_OUT   = 0;
constexpr size_t O_H     = 25600000;
constexpr size_t O_XBF   = 38400000;
constexpr size_t O_WCAT  = 51200000;
constexpr size_t O_EI    = 52084736;
constexpr size_t O_ET    = 56084736;
constexpr size_t O_BAT   = 58084736;
constexpr size_t O_SRC   = 58284736;
constexpr size_t O_DST   = 60284736;
constexpr size_t O_CNT   = 62284736;
constexpr size_t O_RCNT  = 63884736;
constexpr size_t O_SCO   = 65484736;   // scores (N f32); reused early as blockCnt (62.5 KB)
constexpr size_t O_AW    = 65684736;   // attn weights (N f32); reused early as blockOff (62.5 KB)
constexpr size_t O_GEMB  = 65884736;
constexpr size_t O_STATS = 65917504;
constexpr size_t O_MISC  = 65919552;
constexpr size_t WS_NEED = 65919808;

extern "C" void kernel_launch(void* const* d_in, const int* in_sizes, int n_in,
                              void* d_out, int out_size, void* d_ws, size_t ws_size,
                              hipStream_t stream) {
  const void* x     = d_in[0];
  const void* ei    = d_in[1];
  const void* et    = d_in[2];
  const void* batch = d_in[3];
  const void* W1 = d_in[4],  *r1 = d_in[5],  *b1 = d_in[6];
  const void* W2 = d_in[7],  *r2 = d_in[8],  *b2 = d_in[9];
  const void* W3 = d_in[10], *r3 = d_in[11], *b3 = d_in[12];
  const void* g1 = d_in[13], *be1 = d_in[14];
  const void* g2 = d_in[15], *be2 = d_in[16];
  const void* A1 = d_in[17], *a1 = d_in[18];
  const void* A2 = d_in[19], *a2 = d_in[20];
  const void* C1 = d_in[21], *c1 = d_in[22];
  const void* C2 = d_in[23], *c2 = d_in[24];

  if (ws_size < WS_NEED){ k_wsfail<<<1, 1, 0, stream>>>((u32*)d_out); return; }
  char* ws = (char*)d_ws;
  float* out   = (float*)(ws + O_OUT);
  u16*   hbuf  = (u16*)(ws + O_H);
  u16*   xbf   = (u16*)(ws + O_XBF);
  u16*   wcat  = (u16*)(ws + O_WCAT);
  int*   ei_c  = (int*)(ws + O_EI);
  int*   et_c  = (int*)(ws + O_ET);
  int*   bat_c = (int*)(ws + O_BAT);
  u32*   src_s = (u32*)(ws + O_SRC);
  u32*   dst_s = (u32*)(ws + O_DST);
  u32*   cnt   = (u32*)(ws + O_CNT);
  float* rcnt  = (float*)(ws + O_RCNT);
  float* sco   = (float*)(ws + O_SCO);
  float* aw    = (float*)(ws + O_AW);
  u32*   blockCnt = (u32*)(ws + O_SCO);   // early-phase alias
  u32*   blockOff = (u32*)(ws + O_AW);    // early-phase alias
  float* gemb  = (float*)(ws + O_GEMB);
  float* stats = (float*)(ws + O_STATS);
  u32*   misc  = (u32*)(ws + O_MISC);
  u32* relTot = misc;        // 0..7
  u32* relOff = misc + 16;   // 16..24
  u32* smax = misc + 25;
  float* ssum = (float*)(misc + 26);
  u32* flags = misc + 27;
  u32* md = misc + 28;       // md[0]=fmode(f32?), md[1]=imode(int64?)

  hipMemsetAsync(ws + O_CNT, 0, 1600000, stream);
  hipMemsetAsync(ws + O_GEMB, 0, 32768 + 2048 + 256, stream);

  k_fdetect<<<1, 256, 0, stream>>>(x, md);
  k_idetect<<<1, 256, 0, stream>>>(et, md);
  k_icvt<<<6055, 256, 0, stream>>>(ei, et, batch, ei_c, et_c, bat_c, md);
  k_xcvt<<<6250, 256, 0, stream>>>(x, xbf, md, flags);
  k_wcat<<<1728, 256, 0, stream>>>(W1, r1, W2, r2, W3, r3, wcat, md, flags);

  k_count2<<<SORT_B, 256, 0, stream>>>(ei_c, et_c, blockCnt, cnt);
  k_scan<<<1, 64, 0, stream>>>(blockCnt, blockOff, relTot, relOff);
  k_sort2<<<SORT_B, 256, 0, stream>>>(ei_c, et_c, blockOff, relOff, src_s, dst_s);
  k_rcnt<<<(NN * RR + 255) / 256, 256, 0, stream>>>(cnt, rcnt);

  const void* bias[3] = {b1, b2, b3};
  const void* gam[2] = {g1, g2};
  const void* bet[2] = {be1, be2};
  const u16* hin = xbf;
  for (int L = 0; L < 3; L++){
    const u16* wT = wcat + (size_t)L * 128 * 1152;
    k_gemm_root<<<391, 256, 0, stream>>>(hin, wT, bias[L], out, md);
    k_edge<<<dim3(96, 8), 256, 0, stream>>>(hin, wT, src_s, dst_s, relOff, rcnt, out);
    if (L < 2){
      k_bnstats<<<196, 256, 0, stream>>>(out, stats + L * 256);
      k_bnapply<<<6250, 256, 0, stream>>>(out, stats + L * 256, gam[L], bet[L], hbuf, md, flags, 4u << L);
      hin = hbuf;
    }
  }
  k_scores<<<12500, 256, 0, stream>>>(out, A1, a1, A2, a2, sco, md, flags);
  k_max<<<128, 256, 0, stream>>>(sco, smax);
  k_expsum<<<128, 256, 0, stream>>>(sco, smax, aw, ssum, flags);
  k_pool<<<98, 128, 0, stream>>>(out, aw, ssum, bat_c, gemb, flags);
  k_final<<<12500, 256, 0, stream>>>(out, gemb, bat_c, C1, c1, C2, c2, d_out, md, flags);
  k_diag<<<1, 64, 0, stream>>>(relOff, flags, md, d_out);
}

// Round 4
// 1403.808 us; speedup vs baseline: 3.7464x; 1.2055x over previous
//
#include <hip/hip_runtime.h>
#include <hip/hip_bf16.h>

typedef unsigned int u32;
typedef unsigned short u16;
typedef __bf16 bf16_t;
typedef bf16_t bf16x8 __attribute__((ext_vector_type(8)));
typedef float f32x4 __attribute__((ext_vector_type(4)));

constexpr int NN = 50000;
constexpr int EE = 500000;
constexpr int RR = 8;
constexpr int SORT_B = (EE + 255) / 256;   // 1954

// wext element offsets (bf16 elems)
constexpr int WX_A1T = 0;       // [64][128]
constexpr int WX_C1T = 8192;    // [128][256]
constexpr int WX_C2T = 40960;   // [128][128]
constexpr int WX_A2  = 57344;   // [64]
constexpr int WX_a1  = 57408;   // [64]
constexpr int WX_c1  = 57472;   // [128]
constexpr int WX_c2  = 57600;   // [128]
constexpr int WX_a2s = 57728;   // [1]
constexpr int WX_TOT = 57729;

__device__ __forceinline__ float bf2f(u32 v){
  union { u32 u; float f; } x; x.u = (v & 0xFFFFu) << 16; return x.f;
}
__device__ __forceinline__ u16 f2bf(float f){
  union { u32 u; float f; } x; x.f = f;
  u32 r = x.u + 0x7FFFu + ((x.u >> 16) & 1u);
  return (u16)(r >> 16);
}
__device__ __forceinline__ float lrelu(float x){ return x > 0.f ? x : 0.1f * x; }
// mode-aware float load: fm=1 -> f32 source, fm=0 -> bf16 source
__device__ __forceinline__ float ldf(const void* p, int i, u32 fm){
  return fm ? ((const float*)p)[i] : bf2f(((const u16*)p)[i]);
}

// ---------------- dtype detectors ----------------
__global__ void k_fdetect(const void* x, u32* md){
  __shared__ u32 c;
  if (threadIdx.x == 0) c = 0;
  __syncthreads();
  const u16* p = (const u16*)x;
  u32 loc = 0;
  for (int j = 0; j < 16; j++){
    u16 v = p[threadIdx.x * 16 + j];
    u32 e = (v >> 7) & 0xFF;
    if (e >= 0xFD) loc++;
  }
  atomicAdd(&c, loc);
  __syncthreads();
  if (threadIdx.x == 0) md[0] = (c >= 4) ? 1u : 0u;
}
__global__ void k_idetect(const void* et, u32* md){
  __shared__ u32 c;
  if (threadIdx.x == 0) c = 0;
  __syncthreads();
  const int* p = (const int*)et;
  u32 loc = 0;
  for (int j = 0; j < 8; j++){
    int idx = 2 * (threadIdx.x * 8 + j) + 1;
    if (p[idx] != 0) loc++;
  }
  atomicAdd(&c, loc);
  __syncthreads();
  if (threadIdx.x == 0) md[1] = (c == 0) ? 1u : 0u;
}

// ---------------- int conversion -> int32 ws copies
__global__ void k_icvt(const void* ei, const void* et, const void* bat,
                       int* ei_c, int* et_c, int* bat_c, const u32* md){
  u32 im = md[1];
  int i = blockIdx.x * 256 + threadIdx.x;
  if (i < 2 * EE){
    const int* p = (const int*)ei;
    ei_c[i] = im ? p[2 * i] : p[i];
  } else if (i < 3 * EE){
    int j = i - 2 * EE;
    const int* p = (const int*)et;
    et_c[j] = im ? p[2 * j] : p[j];
  } else if (i < 3 * EE + NN){
    int j = i - 3 * EE;
    const int* p = (const int*)bat;
    bat_c[j] = im ? p[2 * j] : p[j];
  }
}

// ---------------- x conversion -> bf16 ws copy (+NaN flag bit1)
__global__ void k_xcvt(const void* x, u16* xb, const u32* md, u32* flags){
  u32 fm = md[0];
  int i4 = (blockIdx.x * 256 + threadIdx.x) * 4;
  if (i4 >= NN * 128) return;
  float v[4];
  if (fm){
    float4 f = *(const float4*)((const float*)x + i4);
    v[0]=f.x; v[1]=f.y; v[2]=f.z; v[3]=f.w;
  } else {
    uint2 u = *(const uint2*)((const u16*)x + i4);
    v[0]=bf2f(u.x); v[1]=bf2f(u.x>>16); v[2]=bf2f(u.y); v[3]=bf2f(u.y>>16);
  }
  bool bad = false;
  u16 o[4];
  for (int j = 0; j < 4; j++){
    if (v[j] != v[j]){ bad = true; v[j] = 0.f; }
    o[j] = f2bf(v[j]);
  }
  unsigned long long bal = __ballot(bad);
  if (bal && (threadIdx.x & 63) == 0) atomicOr(flags, 2u);
  uint2 st;
  st.x = (u32)o[0] | ((u32)o[1] << 16);
  st.y = (u32)o[2] | ((u32)o[3] << 16);
  *(uint2*)(xb + i4) = st;
}

// ---------------- weight transpose: wcatT[L][n][k]; k<1024 -> W[L][k][n], else root[k-1024][n]
__global__ void k_wcat(const void* W1, const void* r1, const void* W2, const void* r2,
                       const void* W3, const void* r3, u16* wcatT, const u32* md, u32* flags){
  u32 fm = md[0];
  int idx = blockIdx.x * 256 + threadIdx.x;
  if (idx >= 3 * 128 * 1152) return;
  int L = idx / (128 * 1152);
  int rem = idx % (128 * 1152);
  int n = rem / 1152, k = rem % 1152;
  const void* W  = (L == 0) ? W1 : ((L == 1) ? W2 : W3);
  const void* rt = (L == 0) ? r1 : ((L == 1) ? r2 : r3);
  float v = (k < 1024) ? ldf(W, k * 128 + n, fm) : ldf(rt, (k - 1024) * 128 + n, fm);
  if (v != v){ v = 0.f; atomicOr(flags, 2u); }
  wcatT[idx] = f2bf(v);
}

// ---------------- small-MLP weight prep: transposed bf16 tables
__global__ void k_wext(const void* A1, const void* a1, const void* A2, const void* a2,
                       const void* C1, const void* c1, const void* C2, const void* c2,
                       u16* wext, const u32* md){
  u32 fm = md[0];
  int idx = blockIdx.x * 256 + threadIdx.x;
  if (idx >= WX_TOT) return;
  float v;
  if (idx < WX_C1T){            // A1T[n][k] = A1[k*64+n]
    int n = idx >> 7, k = idx & 127;
    v = ldf(A1, k * 64 + n, fm);
  } else if (idx < WX_C2T){     // C1T[n][k] = C1[k*128+n]
    int j = idx - WX_C1T; int n = j >> 8, k = j & 255;
    v = ldf(C1, k * 128 + n, fm);
  } else if (idx < WX_A2){      // C2T[n][k] = C2[k*128+n]
    int j = idx - WX_C2T; int n = j >> 7, k = j & 127;
    v = ldf(C2, k * 128 + n, fm);
  } else if (idx < WX_a1){ v = ldf(A2, idx - WX_A2, fm); }
  else if (idx < WX_c1){ v = ldf(a1, idx - WX_a1, fm); }
  else if (idx < WX_c2){ v = ldf(c1, idx - WX_c1, fm); }
  else if (idx < WX_a2s){ v = ldf(c2, idx - WX_c2, fm); }
  else { v = ldf(a2, 0, fm); }
  wext[idx] = f2bf(v);
}

// ---------------- contention-free relation sort ----------------
__global__ void k_count2(const int* __restrict__ ei, const int* __restrict__ et,
                         u32* __restrict__ blockCnt, u32* __restrict__ cnt){
  __shared__ u32 lh[RR];
  if (threadIdx.x < RR) lh[threadIdx.x] = 0;
  __syncthreads();
  int e = blockIdx.x * 256 + threadIdx.x;
  if (e < EE){
    int r = et[e];
    int dst = ei[EE + e];
    atomicAdd(&cnt[dst * RR + r], 1u);
    atomicAdd(&lh[r], 1u);
  }
  __syncthreads();
  if (threadIdx.x < RR) blockCnt[blockIdx.x * RR + threadIdx.x] = lh[threadIdx.x];
}
__global__ void k_scan(const u32* __restrict__ blockCnt, u32* __restrict__ blockOff,
                       u32* __restrict__ relTot, u32* __restrict__ relOff){
  int r = threadIdx.x;
  if (r < RR){
    u32 s = 0;
    for (int b = 0; b < SORT_B; b++){
      blockOff[b * RR + r] = s;
      s += blockCnt[b * RR + r];
    }
    relTot[r] = s;
  }
  __syncthreads();
  if (threadIdx.x == 0){
    u32 s = 0;
    for (int q = 0; q < RR; q++){ relOff[q] = s; s += relTot[q]; }
    relOff[RR] = s;
  }
}
__global__ void k_sort2(const int* __restrict__ ei, const int* __restrict__ et,
                        const u32* __restrict__ blockOff, const u32* __restrict__ relOff,
                        u32* __restrict__ src_s, u32* __restrict__ dst_s){
  __shared__ u32 lh[RR];
  __shared__ u32 base[RR];
  int tid = threadIdx.x;
  if (tid < RR){ lh[tid] = 0; base[tid] = relOff[tid] + blockOff[blockIdx.x * RR + tid]; }
  __syncthreads();
  int e = blockIdx.x * 256 + tid;
  if (e < EE){
    int r = et[e];
    u32 rank = atomicAdd(&lh[r], 1u);
    u32 p = base[r] + rank;
    src_s[p] = (u32)ei[e];
    dst_s[p] = (u32)ei[EE + e];
  }
}

__global__ void k_rcnt(const u32* cnt, float* rcnt){
  int i = blockIdx.x * 256 + threadIdx.x;
  if (i < NN * RR) rcnt[i] = 1.0f / (float)max(cnt[i], 1u);
}

// ---------------- root GEMM: out[N,128] = h@root + bias (plain stores)
#define PADE 8
__global__ __launch_bounds__(256) void k_gemm_root(const u16* __restrict__ h,
                                                   const u16* __restrict__ wT,
                                                   const void* __restrict__ bias,
                                                   float* __restrict__ out, const u32* md){
  __shared__ u16 As[128][64 + PADE];
  __shared__ u16 Bs[128][64 + PADE];
  u32 fm = md[0];
  int m0 = blockIdx.x * 128;
  int tid = threadIdx.x;
  int w = tid >> 6, lane = tid & 63, qd = lane >> 4, l16 = lane & 15;
  f32x4 acc[2][8];
  for (int i = 0; i < 2; i++) for (int j = 0; j < 8; j++) acc[i][j] = (f32x4){0.f,0.f,0.f,0.f};
  for (int k0 = 0; k0 < 128; k0 += 64){
    __syncthreads();
    for (int it = 0; it < 4; it++){
      int lin = it * 2048 + tid * 8;
      int row = lin >> 6, kl = lin & 63;
      int node = m0 + row;
      uint4 v = make_uint4(0u,0u,0u,0u);
      if (node < NN) v = *(const uint4*)(h + node * 128 + k0 + kl);
      *(uint4*)(&As[row][kl]) = v;
      uint4 b = *(const uint4*)(wT + row * 1152 + 1024 + k0 + kl);
      *(uint4*)(&Bs[row][kl]) = b;
    }
    __syncthreads();
    for (int kk = 0; kk < 64; kk += 32){
      bf16x8 a[2], bf[8];
      for (int rt = 0; rt < 2; rt++) a[rt] = *(const bf16x8*)(&As[w * 32 + rt * 16 + l16][kk + qd * 8]);
      for (int ct = 0; ct < 8; ct++) bf[ct] = *(const bf16x8*)(&Bs[ct * 16 + l16][kk + qd * 8]);
      for (int rt = 0; rt < 2; rt++)
        for (int ct = 0; ct < 8; ct++)
          acc[rt][ct] = __builtin_amdgcn_mfma_f32_16x16x32_bf16(a[rt], bf[ct], acc[rt][ct], 0, 0, 0);
    }
  }
  for (int rt = 0; rt < 2; rt++){
    int rbase = m0 + w * 32 + rt * 16 + qd * 4;
    for (int ct = 0; ct < 8; ct++){
      int col = ct * 16 + l16;
      float bv = ldf(bias, col, fm);
      for (int rg = 0; rg < 4; rg++){
        int node = rbase + rg;
        if (node < NN) out[node * 128 + col] = acc[rt][ct][rg] + bv;
      }
    }
  }
}

// ---------------- edge kernel: out[dst] += (h[src] @ W[r]) * rcnt[dst,r]
__global__ __launch_bounds__(256) void k_edge(const u16* __restrict__ h,
                                              const u16* __restrict__ wT,
                                              const u32* __restrict__ src_s,
                                              const u32* __restrict__ dst_s,
                                              const u32* __restrict__ relOff,
                                              const float* __restrict__ rcnt,
                                              float* __restrict__ out){
  __shared__ u16 Ws[128][128 + PADE];
  __shared__ u16 As[32][128 + PADE];
  __shared__ float scL[32];
  __shared__ u32 dstL[32];
  int r = blockIdx.y;
  int tid = threadIdx.x;
  int w = tid >> 6, lane = tid & 63, qd = lane >> 4, l16 = lane & 15;
  for (int it = 0; it < 8; it++){
    int lin = it * 2048 + tid * 8;
    int n = lin >> 7, kl = lin & 127;
    *(uint4*)(&Ws[n][kl]) = *(const uint4*)(wT + n * 1152 + r * 128 + kl);
  }
  u32 start = relOff[r], end = relOff[r + 1];
  int ntiles = (int)(end - start + 31) >> 5;
  int mt = w & 1, nb = (w >> 1) * 4;
  for (int t = blockIdx.x; t < ntiles; t += gridDim.x){
    u32 e0 = start + ((u32)t << 5);
    int mvalid = min(32, (int)(end - e0));
    __syncthreads();
    {
      int row = tid >> 3, seg = tid & 7;
      uint4 v0 = make_uint4(0u,0u,0u,0u), v1 = v0;
      if (row < mvalid){
        u32 src = src_s[e0 + row];
        const u16* p = h + src * 128 + seg * 16;
        v0 = *(const uint4*)(p);
        v1 = *(const uint4*)(p + 8);
      }
      *(uint4*)(&As[row][seg * 16]) = v0;
      *(uint4*)(&As[row][seg * 16 + 8]) = v1;
      if (tid < 32){
        if (tid < mvalid){
          u32 d = dst_s[e0 + tid];
          dstL[tid] = d;
          scL[tid] = rcnt[d * RR + r];
        } else { dstL[tid] = 0; scL[tid] = 0.f; }
      }
    }
    __syncthreads();
    f32x4 acc[4];
    for (int i = 0; i < 4; i++) acc[i] = (f32x4){0.f,0.f,0.f,0.f};
    for (int kk = 0; kk < 128; kk += 32){
      bf16x8 a = *(const bf16x8*)(&As[mt * 16 + l16][kk + qd * 8]);
      for (int i = 0; i < 4; i++){
        bf16x8 b = *(const bf16x8*)(&Ws[(nb + i) * 16 + l16][kk + qd * 8]);
        acc[i] = __builtin_amdgcn_mfma_f32_16x16x32_bf16(a, b, acc[i], 0, 0, 0);
      }
    }
    for (int i = 0; i < 4; i++){
      int col = (nb + i) * 16 + l16;
      for (int rg = 0; rg < 4; rg++){
        int er = mt * 16 + qd * 4 + rg;
        if (er < mvalid)
          unsafeAtomicAdd(&out[dstL[er] * 128 + col], acc[i][rg] * scL[er]);
      }
    }
  }
}

// ---------------- BatchNorm
__global__ void k_bnstats(const float* __restrict__ out, float* __restrict__ stats){
  __shared__ float sb[256], sb2[256];
  int tid = threadIdx.x;
  int col = tid & 127, half = tid >> 7;
  int r0 = blockIdx.x * 256;
  float s = 0.f, s2 = 0.f;
  for (int i = half; i < 256; i += 2){
    int n = r0 + i;
    if (n < NN){ float v = out[n * 128 + col]; s += v; s2 += v * v; }
  }
  sb[tid] = s; sb2[tid] = s2;
  __syncthreads();
  if (half == 0){
    unsafeAtomicAdd(&stats[col],       sb[col] + sb[col + 128]);
    unsafeAtomicAdd(&stats[128 + col], sb2[col] + sb2[col + 128]);
  }
}

__global__ void k_bnapply(const float* __restrict__ out, const float* __restrict__ stats,
                          const void* __restrict__ g, const void* __restrict__ beta,
                          u16* __restrict__ hout, const u32* md, u32* flags, u32 layerbit){
  u32 fm = md[0];
  int idx = (blockIdx.x * 256 + threadIdx.x) * 4;
  if (idx >= NN * 128) return;
  int col = idx & 127;
  float4 v = *(const float4*)(out + idx);
  float vv[4] = {v.x, v.y, v.z, v.w};
  bool bad = false;
  u16 o[4];
  for (int j = 0; j < 4; j++){
    int c = col + j;
    float mu = stats[c] * (1.0f / NN);
    float var = fmaxf(stats[128 + c] * (1.0f / NN) - mu * mu, 0.f);
    float sc = ldf(g, c, fm) * rsqrtf(var + 1e-5f);
    float sh = ldf(beta, c, fm) - mu * sc;
    float r = vv[j] * sc + sh;
    if (r != r || sc != sc){ bad = true; r = 0.f; }
    o[j] = f2bf(lrelu(r));
  }
  unsigned long long bal = __ballot(bad);
  if (bal && (threadIdx.x & 63) == 0) atomicOr(flags, layerbit);
  uint2 st;
  st.x = (u32)o[0] | ((u32)o[1] << 16);
  st.y = (u32)o[2] | ((u32)o[3] << 16);
  *(uint2*)(hout + idx) = st;
}

// ---------------- attention scores via MFMA: scores = lrelu(emb@A1+a1)@A2 + a2
__global__ __launch_bounds__(256) void k_scores_mfma(const float* __restrict__ emb,
                                                     const u16* __restrict__ wext,
                                                     float* __restrict__ scores){
  __shared__ u16 As[128][136];
  int m0 = blockIdx.x * 128;
  int tid = threadIdx.x;
  int w = tid >> 6, lane = tid & 63, qd = lane >> 4, l16 = lane & 15;
  for (int it = 0; it < 16; it++){
    int lin = it * 1024 + tid * 4;
    int row = lin >> 7, c = lin & 127;
    int node = m0 + row;
    float4 v = make_float4(0.f,0.f,0.f,0.f);
    if (node < NN) v = *(const float4*)(emb + (size_t)node * 128 + c);
    uint2 st;
    st.x = (u32)f2bf(v.x) | ((u32)f2bf(v.y) << 16);
    st.y = (u32)f2bf(v.z) | ((u32)f2bf(v.w) << 16);
    *(uint2*)(&As[row][c]) = st;
  }
  __syncthreads();
  f32x4 acc[2][4];
  for (int i = 0; i < 2; i++) for (int j = 0; j < 4; j++) acc[i][j] = (f32x4){0.f,0.f,0.f,0.f};
  for (int k0 = 0; k0 < 4; k0++){
    bf16x8 a[2];
    a[0] = *(const bf16x8*)(&As[(w * 2) * 16 + l16][k0 * 32 + qd * 8]);
    a[1] = *(const bf16x8*)(&As[(w * 2 + 1) * 16 + l16][k0 * 32 + qd * 8]);
    for (int ct = 0; ct < 4; ct++){
      bf16x8 b = *(const bf16x8*)(wext + WX_A1T + (size_t)(ct * 16 + l16) * 128 + k0 * 32 + qd * 8);
      acc[0][ct] = __builtin_amdgcn_mfma_f32_16x16x32_bf16(a[0], b, acc[0][ct], 0, 0, 0);
      acc[1][ct] = __builtin_amdgcn_mfma_f32_16x16x32_bf16(a[1], b, acc[1][ct], 0, 0, 0);
    }
  }
  float a1v[4], a2v[4];
  for (int ct = 0; ct < 4; ct++){
    a1v[ct] = bf2f(wext[WX_a1 + ct * 16 + l16]);
    a2v[ct] = bf2f(wext[WX_A2 + ct * 16 + l16]);
  }
  float a2s = bf2f(wext[WX_a2s]);
  for (int rt = 0; rt < 2; rt++)
    for (int rg = 0; rg < 4; rg++){
      float s = 0.f;
      for (int ct = 0; ct < 4; ct++)
        s += lrelu(acc[rt][ct][rg] + a1v[ct]) * a2v[ct];
      s += __shfl_xor(s, 1); s += __shfl_xor(s, 2);
      s += __shfl_xor(s, 4); s += __shfl_xor(s, 8);
      int row = m0 + (w * 2 + rt) * 16 + qd * 4 + rg;
      if (l16 == 0 && row < NN) scores[row] = s + a2s;
    }
}

__device__ __forceinline__ u32 fmap(float f){
  union{u32 u; float f;} x; x.f = f;
  return (x.u & 0x80000000u) ? ~x.u : (x.u | 0x80000000u);
}
__device__ __forceinline__ float funmap(u32 m){
  union{u32 u; float f;} x;
  x.u = (m & 0x80000000u) ? (m ^ 0x80000000u) : ~m;
  return x.f;
}

__global__ void k_max(const float* __restrict__ scores, u32* smax){
  int gid = blockIdx.x * 256 + threadIdx.x;
  float m = -1e30f;
  for (int i = gid; i < NN; i += 256 * 128) m = fmaxf(m, scores[i]);
  for (int off = 32; off; off >>= 1) m = fmaxf(m, __shfl_down(m, off));
  if ((threadIdx.x & 63) == 0) atomicMax(smax, fmap(m));
}

__global__ void k_expsum(const float* __restrict__ scores, const u32* smax,
                         float* __restrict__ attnw, float* ssum, u32* flags){
  float mx = funmap(*smax);
  int gid = blockIdx.x * 256 + threadIdx.x;
  if (mx != mx){ if (gid == 0) atomicOr(flags, 32u); mx = 0.f; }
  float s = 0.f;
  bool bad = false;
  for (int i = gid; i < NN; i += 256 * 128){
    float e = __expf(scores[i] - mx);
    if (e != e){ bad = true; e = 0.f; }
    attnw[i] = e; s += e;
  }
  unsigned long long bal = __ballot(bad);
  if (bal && (threadIdx.x & 63) == 0) atomicOr(flags, 32u);
  for (int off = 32; off; off >>= 1) s += __shfl_down(s, off);
  if ((threadIdx.x & 63) == 0) unsafeAtomicAdd(ssum, s);
}

// ---------------- pooling: batch sorted; running per-graph accumulation
__global__ __launch_bounds__(128) void k_pool(const float* __restrict__ emb,
                                              const float* __restrict__ attnw,
                                              const float* __restrict__ ssum,
                                              const int* __restrict__ batch,
                                              float* __restrict__ gemb, u32* flags){
  int t = threadIdx.x;
  int n0 = blockIdx.x * 512;
  if (n0 >= NN) return;
  int n1 = min(n0 + 512, NN);
  float sv = *ssum;
  bool bad = !(sv > 0.f) || (sv != sv);
  if (bad && t == 0 && blockIdx.x == 0) atomicOr(flags, 64u);
  float rs = bad ? 0.f : 1.0f / sv;
  int cur = batch[n0];
  float acc = 0.f;
  for (int n = n0; n < n1; n++){
    int b = batch[n];
    if (b != cur){ unsafeAtomicAdd(&gemb[cur * 128 + t], acc * rs); acc = 0.f; cur = b; }
    acc += emb[n * 128 + t] * attnw[n];
  }
  unsafeAtomicAdd(&gemb[cur * 128 + t], acc * rs);
}

// ---------------- final combiner via MFMA + row L2 normalize
// GEMM1: [128,256]@C1T -> lrelu -> Hs; GEMM2: Hs@C2T -> norm -> out
__global__ __launch_bounds__(256) void k_final_mfma(const float* __restrict__ emb,
                                                    const float* __restrict__ gemb,
                                                    const int* __restrict__ batch,
                                                    const u16* __restrict__ wext,
                                                    void* __restrict__ outp,
                                                    const u32* md){
  __shared__ u16 As[128][264];
  u16 (*Hs)[136] = (u16(*)[136])(&As[0][0]);   // alias: reused after GEMM1
  u32 fm = md[0];
  int m0 = blockIdx.x * 128;
  int tid = threadIdx.x;
  int w = tid >> 6, lane = tid & 63, qd = lane >> 4, l16 = lane & 15;
  for (int it = 0; it < 32; it++){
    int lin = it * 1024 + tid * 4;
    int row = lin >> 8, c = lin & 255;
    int node = m0 + row;
    float4 v = make_float4(0.f,0.f,0.f,0.f);
    if (node < NN){
      if (c < 128) v = *(const float4*)(emb + (size_t)node * 128 + c);
      else { int g = batch[node]; v = *(const float4*)(gemb + (size_t)g * 128 + (c - 128)); }
    }
    uint2 st;
    st.x = (u32)f2bf(v.x) | ((u32)f2bf(v.y) << 16);
    st.y = (u32)f2bf(v.z) | ((u32)f2bf(v.w) << 16);
    *(uint2*)(&As[row][c]) = st;
  }
  __syncthreads();
  f32x4 acc[2][8];
  for (int i = 0; i < 2; i++) for (int j = 0; j < 8; j++) acc[i][j] = (f32x4){0.f,0.f,0.f,0.f};
  for (int k0 = 0; k0 < 8; k0++){
    bf16x8 a[2];
    a[0] = *(const bf16x8*)(&As[(w * 2) * 16 + l16][k0 * 32 + qd * 8]);
    a[1] = *(const bf16x8*)(&As[(w * 2 + 1) * 16 + l16][k0 * 32 + qd * 8]);
    for (int ct = 0; ct < 8; ct++){
      bf16x8 b = *(const bf16x8*)(wext + WX_C1T + (size_t)(ct * 16 + l16) * 256 + k0 * 32 + qd * 8);
      acc[0][ct] = __builtin_amdgcn_mfma_f32_16x16x32_bf16(a[0], b, acc[0][ct], 0, 0, 0);
      acc[1][ct] = __builtin_amdgcn_mfma_f32_16x16x32_bf16(a[1], b, acc[1][ct], 0, 0, 0);
    }
  }
  __syncthreads();   // all As reads complete before Hs overwrites the same LDS
  for (int rt = 0; rt < 2; rt++)
    for (int ct = 0; ct < 8; ct++){
      float c1v = bf2f(wext[WX_c1 + ct * 16 + l16]);
      for (int rg = 0; rg < 4; rg++){
        int row = (w * 2 + rt) * 16 + qd * 4 + rg;
        Hs[row][ct * 16 + l16] = f2bf(lrelu(acc[rt][ct][rg] + c1v));
      }
    }
  __syncthreads();
  f32x4 acc2[2][8];
  for (int i = 0; i < 2; i++) for (int j = 0; j < 8; j++) acc2[i][j] = (f32x4){0.f,0.f,0.f,0.f};
  for (int k0 = 0; k0 < 4; k0++){
    bf16x8 a[2];
    a[0] = *(const bf16x8*)(&Hs[(w * 2) * 16 + l16][k0 * 32 + qd * 8]);
    a[1] = *(const bf16x8*)(&Hs[(w * 2 + 1) * 16 + l16][k0 * 32 + qd * 8]);
    for (int ct = 0; ct < 8; ct++){
      bf16x8 b = *(const bf16x8*)(wext + WX_C2T + (size_t)(ct * 16 + l16) * 128 + k0 * 32 + qd * 8);
      acc2[0][ct] = __builtin_amdgcn_mfma_f32_16x16x32_bf16(a[0], b, acc2[0][ct], 0, 0, 0);
      acc2[1][ct] = __builtin_amdgcn_mfma_f32_16x16x32_bf16(a[1], b, acc2[1][ct], 0, 0, 0);
    }
  }
  float c2v[8];
  for (int ct = 0; ct < 8; ct++) c2v[ct] = bf2f(wext[WX_c2 + ct * 16 + l16]);
  for (int rt = 0; rt < 2; rt++)
    for (int rg = 0; rg < 4; rg++){
      float ss = 0.f;
      for (int ct = 0; ct < 8; ct++){
        float o = acc2[rt][ct][rg] + c2v[ct];
        ss += o * o;
      }
      ss += __shfl_xor(ss, 1); ss += __shfl_xor(ss, 2);
      ss += __shfl_xor(ss, 4); ss += __shfl_xor(ss, 8);
      float sc = 1.0f / fmaxf(sqrtf(ss), 1e-12f);
      int row = m0 + (w * 2 + rt) * 16 + qd * 4 + rg;
      if (row < NN){
        if (fm){
          float* op = (float*)outp;
          for (int ct = 0; ct < 8; ct++)
            op[(size_t)row * 128 + ct * 16 + l16] = (acc2[rt][ct][rg] + c2v[ct]) * sc;
        } else {
          u16* op = (u16*)outp;
          for (int ct = 0; ct < 8; ct++)
            op[(size_t)row * 128 + ct * 16 + l16] = f2bf((acc2[rt][ct][rg] + c2v[ct]) * sc);
        }
      }
    }
}

// ---------------- diag sentinels: only touches out if something is broken
__global__ void k_diag(const u32* relOff, const u32* flags, const u32* md, void* outp){
  if (threadIdx.x != 0 || blockIdx.x != 0) return;
  u32 fm = md[0];
  u32 f = flags[0];
  if (relOff[RR] != (u32)EE) f |= 1u;
  for (int b = 0; b < 9; b++){
    if (f & (1u << b)){
      float s = (float)(131072 >> b);
      if (fm) ((float*)outp)[b] = s;
      else ((u16*)outp)[b] = f2bf(s);
    }
  }
}
__global__ void k_wsfail(u32* outp){ outp[0] = 0x43000000u; }

// ---------------- workspace layout (bytes)
constexpr size_t O_OUT   = 0;
constexpr size_t O_H     = 25600000;
constexpr size_t O_XBF   = 38400000;
constexpr size_t O_WCAT  = 51200000;
constexpr size_t O_WEXT  = 52084736;   // 115,712 B (57,856 elems bf16, rounded)
constexpr size_t O_EI    = 52200448;
constexpr size_t O_ET    = 56200448;
constexpr size_t O_BAT   = 58200448;
constexpr size_t O_SRC   = 58400448;
constexpr size_t O_DST   = 60400448;
constexpr size_t O_CNT   = 62400448;
constexpr size_t O_RCNT  = 64000448;
constexpr size_t O_SCO   = 65600448;   // scores (N f32); early alias: blockCnt
constexpr size_t O_AW    = 65800448;   // attn weights (N f32); early alias: blockOff
constexpr size_t O_GEMB  = 66000448;
constexpr size_t O_STATS = 66033216;
constexpr size_t O_MISC  = 66035264;
constexpr size_t WS_NEED = 66035520;

extern "C" void kernel_launch(void* const* d_in, const int* in_sizes, int n_in,
                              void* d_out, int out_size, void* d_ws, size_t ws_size,
                              hipStream_t stream) {
  const void* x     = d_in[0];
  const void* ei    = d_in[1];
  const void* et    = d_in[2];
  const void* batch = d_in[3];
  const void* W1 = d_in[4],  *r1 = d_in[5],  *b1 = d_in[6];
  const void* W2 = d_in[7],  *r2 = d_in[8],  *b2 = d_in[9];
  const void* W3 = d_in[10], *r3 = d_in[11], *b3 = d_in[12];
  const void* g1 = d_in[13], *be1 = d_in[14];
  const void* g2 = d_in[15], *be2 = d_in[16];
  const void* A1 = d_in[17], *a1 = d_in[18];
  const void* A2 = d_in[19], *a2 = d_in[20];
  const void* C1 = d_in[21], *c1 = d_in[22];
  const void* C2 = d_in[23], *c2 = d_in[24];

  if (ws_size < WS_NEED){ k_wsfail<<<1, 1, 0, stream>>>((u32*)d_out); return; }
  char* ws = (char*)d_ws;
  float* out   = (float*)(ws + O_OUT);
  u16*   hbuf  = (u16*)(ws + O_H);
  u16*   xbf   = (u16*)(ws + O_XBF);
  u16*   wcat  = (u16*)(ws + O_WCAT);
  u16*   wext  = (u16*)(ws + O_WEXT);
  int*   ei_c  = (int*)(ws + O_EI);
  int*   et_c  = (int*)(ws + O_ET);
  int*   bat_c = (int*)(ws + O_BAT);
  u32*   src_s = (u32*)(ws + O_SRC);
  u32*   dst_s = (u32*)(ws + O_DST);
  u32*   cnt   = (u32*)(ws + O_CNT);
  float* rcnt  = (float*)(ws + O_RCNT);
  float* sco   = (float*)(ws + O_SCO);
  float* aw    = (float*)(ws + O_AW);
  u32*   blockCnt = (u32*)(ws + O_SCO);   // early-phase alias
  u32*   blockOff = (u32*)(ws + O_AW);    // early-phase alias
  float* gemb  = (float*)(ws + O_GEMB);
  float* stats = (float*)(ws + O_STATS);
  u32*   misc  = (u32*)(ws + O_MISC);
  u32* relTot = misc;        // 0..7
  u32* relOff = misc + 16;   // 16..24
  u32* smax = misc + 25;
  float* ssum = (float*)(misc + 26);
  u32* flags = misc + 27;
  u32* md = misc + 28;       // md[0]=fmode(f32?), md[1]=imode(int64?)

  hipMemsetAsync(ws + O_CNT, 0, 1600000, stream);
  hipMemsetAsync(ws + O_GEMB, 0, 32768 + 2048 + 256, stream);

  k_fdetect<<<1, 256, 0, stream>>>(x, md);
  k_idetect<<<1, 256, 0, stream>>>(et, md);
  k_icvt<<<6055, 256, 0, stream>>>(ei, et, batch, ei_c, et_c, bat_c, md);
  k_xcvt<<<6250, 256, 0, stream>>>(x, xbf, md, flags);
  k_wcat<<<1728, 256, 0, stream>>>(W1, r1, W2, r2, W3, r3, wcat, md, flags);
  k_wext<<<227, 256, 0, stream>>>(A1, a1, A2, a2, C1, c1, C2, c2, wext, md);

  k_count2<<<SORT_B, 256, 0, stream>>>(ei_c, et_c, blockCnt, cnt);
  k_scan<<<1, 64, 0, stream>>>(blockCnt, blockOff, relTot, relOff);
  k_sort2<<<SORT_B, 256, 0, stream>>>(ei_c, et_c, blockOff, relOff, src_s, dst_s);
  k_rcnt<<<(NN * RR + 255) / 256, 256, 0, stream>>>(cnt, rcnt);

  const void* bias[3] = {b1, b2, b3};
  const void* gam[2] = {g1, g2};
  const void* bet[2] = {be1, be2};
  const u16* hin = xbf;
  for (int L = 0; L < 3; L++){
    const u16* wT = wcat + (size_t)L * 128 * 1152;
    k_gemm_root<<<391, 256, 0, stream>>>(hin, wT, bias[L], out, md);
    k_edge<<<dim3(96, 8), 256, 0, stream>>>(hin, wT, src_s, dst_s, relOff, rcnt, out);
    if (L < 2){
      k_bnstats<<<196, 256, 0, stream>>>(out, stats + L * 256);
      k_bnapply<<<6250, 256, 0, stream>>>(out, stats + L * 256, gam[L], bet[L], hbuf, md, flags, 4u << L);
      hin = hbuf;
    }
  }
  k_scores_mfma<<<391, 256, 0, stream>>>(out, wext, sco);
  k_max<<<128, 256, 0, stream>>>(sco, smax);
  k_expsum<<<128, 256, 0, stream>>>(sco, smax, aw, ssum, flags);
  k_pool<<<98, 128, 0, stream>>>(out, aw, ssum, bat_c, gemb, flags);
  k_final_mfma<<<391, 256, 0, stream>>>(out, gemb, bat_c, wext, d_out, md);
  k_diag<<<1, 64, 0, stream>>>(relOff, flags, md, d_out);
}

// Round 5
// 1098.622 us; speedup vs baseline: 4.7871x; 1.2778x over previous
//
#include <hip/hip_runtime.h>
#include <hip/hip_bf16.h>

typedef unsigned int u32;
typedef unsigned short u16;
typedef __bf16 bf16_t;
typedef bf16_t bf16x8 __attribute__((ext_vector_type(8)));
typedef float f32x4 __attribute__((ext_vector_type(4)));

constexpr int NN = 50000;
constexpr int EE = 500000;
constexpr int RR = 8;
constexpr int NKEY = RR * NN;               // 400000
constexpr int PAIR_B = (NKEY + 511) / 512;  // 782

// wext element offsets (bf16 elems)
constexpr int WX_A1T = 0;       // [64][128]
constexpr int WX_C1T = 8192;    // [128][256]
constexpr int WX_C2T = 40960;   // [128][128]
constexpr int WX_A2  = 57344;   // [64]
constexpr int WX_a1  = 57408;   // [64]
constexpr int WX_c1  = 57472;   // [128]
constexpr int WX_c2  = 57600;   // [128]
constexpr int WX_a2s = 57728;   // [1]
constexpr int WX_TOT = 57729;

__device__ __forceinline__ float bf2f(u32 v){
  union { u32 u; float f; } x; x.u = (v & 0xFFFFu) << 16; return x.f;
}
__device__ __forceinline__ u16 f2bf(float f){
  union { u32 u; float f; } x; x.f = f;
  u32 r = x.u + 0x7FFFu + ((x.u >> 16) & 1u);
  return (u16)(r >> 16);
}
__device__ __forceinline__ float lrelu(float x){ return x > 0.f ? x : 0.1f * x; }
__device__ __forceinline__ float ldf(const void* p, int i, u32 fm){
  return fm ? ((const float*)p)[i] : bf2f(((const u16*)p)[i]);
}

// ---------------- dtype detectors ----------------
__global__ void k_fdetect(const void* x, u32* md){
  __shared__ u32 c;
  if (threadIdx.x == 0) c = 0;
  __syncthreads();
  const u16* p = (const u16*)x;
  u32 loc = 0;
  for (int j = 0; j < 16; j++){
    u16 v = p[threadIdx.x * 16 + j];
    u32 e = (v >> 7) & 0xFF;
    if (e >= 0xFD) loc++;
  }
  atomicAdd(&c, loc);
  __syncthreads();
  if (threadIdx.x == 0) md[0] = (c >= 4) ? 1u : 0u;
}
__global__ void k_idetect(const void* et, u32* md){
  __shared__ u32 c;
  if (threadIdx.x == 0) c = 0;
  __syncthreads();
  const int* p = (const int*)et;
  u32 loc = 0;
  for (int j = 0; j < 8; j++){
    int idx = 2 * (threadIdx.x * 8 + j) + 1;
    if (p[idx] != 0) loc++;
  }
  atomicAdd(&c, loc);
  __syncthreads();
  if (threadIdx.x == 0) md[1] = (c == 0) ? 1u : 0u;
}

// ---------------- int conversion -> int32 ws copies
__global__ void k_icvt(const void* ei, const void* et, const void* bat,
                       int* ei_c, int* et_c, int* bat_c, const u32* md){
  u32 im = md[1];
  int i = blockIdx.x * 256 + threadIdx.x;
  if (i < 2 * EE){
    const int* p = (const int*)ei;
    ei_c[i] = im ? p[2 * i] : p[i];
  } else if (i < 3 * EE){
    int j = i - 2 * EE;
    const int* p = (const int*)et;
    et_c[j] = im ? p[2 * j] : p[j];
  } else if (i < 3 * EE + NN){
    int j = i - 3 * EE;
    const int* p = (const int*)bat;
    bat_c[j] = im ? p[2 * j] : p[j];
  }
}

// ---------------- x conversion -> bf16 ws copy (+NaN flag bit1)
__global__ void k_xcvt(const void* x, u16* xb, const u32* md, u32* flags){
  u32 fm = md[0];
  int i4 = (blockIdx.x * 256 + threadIdx.x) * 4;
  if (i4 >= NN * 128) return;
  float v[4];
  if (fm){
    float4 f = *(const float4*)((const float*)x + i4);
    v[0]=f.x; v[1]=f.y; v[2]=f.z; v[3]=f.w;
  } else {
    uint2 u = *(const uint2*)((const u16*)x + i4);
    v[0]=bf2f(u.x); v[1]=bf2f(u.x>>16); v[2]=bf2f(u.y); v[3]=bf2f(u.y>>16);
  }
  bool bad = false;
  u16 o[4];
  for (int j = 0; j < 4; j++){
    if (v[j] != v[j]){ bad = true; v[j] = 0.f; }
    o[j] = f2bf(v[j]);
  }
  unsigned long long bal = __ballot(bad);
  if (bal && (threadIdx.x & 63) == 0) atomicOr(flags, 2u);
  uint2 st;
  st.x = (u32)o[0] | ((u32)o[1] << 16);
  st.y = (u32)o[2] | ((u32)o[3] << 16);
  *(uint2*)(xb + i4) = st;
}

// ---------------- weight transpose: wcatT[L][n][k]; k<1024 -> W[L][k][n], else root[k-1024][n]
__global__ void k_wcat(const void* W1, const void* r1, const void* W2, const void* r2,
                       const void* W3, const void* r3, u16* wcatT, const u32* md, u32* flags){
  u32 fm = md[0];
  int idx = blockIdx.x * 256 + threadIdx.x;
  if (idx >= 3 * 128 * 1152) return;
  int L = idx / (128 * 1152);
  int rem = idx % (128 * 1152);
  int n = rem / 1152, k = rem % 1152;
  const void* W  = (L == 0) ? W1 : ((L == 1) ? W2 : W3);
  const void* rt = (L == 0) ? r1 : ((L == 1) ? r2 : r3);
  float v = (k < 1024) ? ldf(W, k * 128 + n, fm) : ldf(rt, (k - 1024) * 128 + n, fm);
  if (v != v){ v = 0.f; atomicOr(flags, 2u); }
  wcatT[idx] = f2bf(v);
}

// ---------------- small-MLP weight prep: transposed bf16 tables
__global__ void k_wext(const void* A1, const void* a1, const void* A2, const void* a2,
                       const void* C1, const void* c1, const void* C2, const void* c2,
                       u16* wext, const u32* md){
  u32 fm = md[0];
  int idx = blockIdx.x * 256 + threadIdx.x;
  if (idx >= WX_TOT) return;
  float v;
  if (idx < WX_C1T){
    int n = idx >> 7, k = idx & 127;
    v = ldf(A1, k * 64 + n, fm);
  } else if (idx < WX_C2T){
    int j = idx - WX_C1T; int n = j >> 8, k = j & 255;
    v = ldf(C1, k * 128 + n, fm);
  } else if (idx < WX_A2){
    int j = idx - WX_C2T; int n = j >> 7, k = j & 127;
    v = ldf(C2, k * 128 + n, fm);
  } else if (idx < WX_a1){ v = ldf(A2, idx - WX_A2, fm); }
  else if (idx < WX_c1){ v = ldf(a1, idx - WX_a1, fm); }
  else if (idx < WX_c2){ v = ldf(c1, idx - WX_c1, fm); }
  else if (idx < WX_a2s){ v = ldf(c2, idx - WX_c2, fm); }
  else { v = ldf(a2, 0, fm); }
  wext[idx] = f2bf(v);
}

// ---------------- (rel,dst) counting sort ----------------
__global__ void k_count3(const int* __restrict__ ei, const int* __restrict__ et, u32* __restrict__ cnt){
  int e = blockIdx.x * 256 + threadIdx.x;
  if (e >= EE) return;
  atomicAdd(&cnt[ei[EE + e] * RR + et[e]], 1u);
}
// key = r*NN + d ; count(key) = cnt[d*8+r]. Phase A: 512-key block sums.
__global__ void k_pairA(const u32* __restrict__ cnt, u32* __restrict__ blockSum){
  __shared__ u32 sd[256];
  int b = blockIdx.x, t = threadIdx.x;
  u32 s = 0;
  for (int j = 0; j < 2; j++){
    int key = b * 512 + t * 2 + j;
    if (key < NKEY){ int r = key / NN, d = key % NN; s += cnt[d * RR + r]; }
  }
  sd[t] = s; __syncthreads();
  for (int off = 128; off; off >>= 1){ if (t < off) sd[t] += sd[t + off]; __syncthreads(); }
  if (t == 0) blockSum[b] = sd[0];
}
// Phase B: one-wave scan over PAIR_B block sums
__global__ void k_pairB(const u32* __restrict__ blockSum, u32* __restrict__ blockBase){
  int lane = threadIdx.x;   // 64
  u32 loc[13]; u32 s = 0;
  for (int j = 0; j < 13; j++){
    int b = lane * 13 + j;
    u32 v = (b < PAIR_B) ? blockSum[b] : 0u;
    loc[j] = s; s += v;
  }
  u32 tot = s;
  for (int off = 1; off < 64; off <<= 1){
    u32 x = __shfl_up(tot, off);
    if (lane >= off) tot += x;
  }
  u32 excl = tot - s;
  for (int j = 0; j < 13; j++){
    int b = lane * 13 + j;
    if (b < PAIR_B) blockBase[b] = excl + loc[j];
  }
}
// Phase C: per-key exclusive prefix (pairStart) + zero cursor
__global__ void k_pairC(const u32* __restrict__ cnt, const u32* __restrict__ blockBase,
                        u32* __restrict__ pairStart, u32* __restrict__ cursor){
  __shared__ u32 sd[256];
  int b = blockIdx.x, t = threadIdx.x;
  int k0 = b * 512 + t * 2;
  u32 v0 = 0, v1 = 0;
  if (k0 < NKEY){ int r = k0 / NN, d = k0 % NN; v0 = cnt[d * RR + r]; }
  if (k0 + 1 < NKEY){ int r = (k0 + 1) / NN, d = (k0 + 1) % NN; v1 = cnt[d * RR + r]; }
  sd[t] = v0 + v1; __syncthreads();
  for (int off = 1; off < 256; off <<= 1){
    u32 x = (t >= off) ? sd[t - off] : 0u;
    __syncthreads();
    sd[t] += x;
    __syncthreads();
  }
  u32 excl = sd[t] - (v0 + v1);
  u32 base = blockBase[b] + excl;
  if (k0 < NKEY){ pairStart[k0] = base; cursor[k0] = 0u; }
  if (k0 + 1 < NKEY){ pairStart[k0 + 1] = base + v0; cursor[k0 + 1] = 0u; }
}
__global__ void k_reloff(const u32* __restrict__ pairStart, u32* __restrict__ relOff){
  int t = threadIdx.x;
  if (t < RR) relOff[t] = pairStart[t * NN];
  if (t == RR) relOff[RR] = (u32)EE;
}
__global__ void k_sort3(const int* __restrict__ ei, const int* __restrict__ et,
                        const u32* __restrict__ pairStart, u32* __restrict__ cursor,
                        u32* __restrict__ src_s, u32* __restrict__ dst_s){
  int e = blockIdx.x * 256 + threadIdx.x;
  if (e >= EE) return;
  int r = et[e], d = ei[EE + e];
  u32 key = (u32)r * NN + (u32)d;
  u32 p = pairStart[key] + atomicAdd(&cursor[key], 1u);
  src_s[p] = (u32)ei[e];
  dst_s[p] = (u32)d;
}

__global__ void k_rcnt(const u32* cnt, float* rcnt){
  int i = blockIdx.x * 256 + threadIdx.x;
  if (i < NN * RR) rcnt[i] = 1.0f / (float)max(cnt[i], 1u);
}

// ---------------- root GEMM: out[N,128] = h@root + bias (plain stores)
#define PADE 8
__global__ __launch_bounds__(256) void k_gemm_root(const u16* __restrict__ h,
                                                   const u16* __restrict__ wT,
                                                   const void* __restrict__ bias,
                                                   float* __restrict__ out, const u32* md){
  __shared__ u16 As[128][64 + PADE];
  __shared__ u16 Bs[128][64 + PADE];
  u32 fm = md[0];
  int m0 = blockIdx.x * 128;
  int tid = threadIdx.x;
  int w = tid >> 6, lane = tid & 63, qd = lane >> 4, l16 = lane & 15;
  f32x4 acc[2][8];
  for (int i = 0; i < 2; i++) for (int j = 0; j < 8; j++) acc[i][j] = (f32x4){0.f,0.f,0.f,0.f};
  for (int k0 = 0; k0 < 128; k0 += 64){
    __syncthreads();
    for (int it = 0; it < 4; it++){
      int lin = it * 2048 + tid * 8;
      int row = lin >> 6, kl = lin & 63;
      int node = m0 + row;
      uint4 v = make_uint4(0u,0u,0u,0u);
      if (node < NN) v = *(const uint4*)(h + node * 128 + k0 + kl);
      *(uint4*)(&As[row][kl]) = v;
      uint4 b = *(const uint4*)(wT + row * 1152 + 1024 + k0 + kl);
      *(uint4*)(&Bs[row][kl]) = b;
    }
    __syncthreads();
    for (int kk = 0; kk < 64; kk += 32){
      bf16x8 a[2], bf[8];
      for (int rt = 0; rt < 2; rt++) a[rt] = *(const bf16x8*)(&As[w * 32 + rt * 16 + l16][kk + qd * 8]);
      for (int ct = 0; ct < 8; ct++) bf[ct] = *(const bf16x8*)(&Bs[ct * 16 + l16][kk + qd * 8]);
      for (int rt = 0; rt < 2; rt++)
        for (int ct = 0; ct < 8; ct++)
          acc[rt][ct] = __builtin_amdgcn_mfma_f32_16x16x32_bf16(a[rt], bf[ct], acc[rt][ct], 0, 0, 0);
    }
  }
  for (int rt = 0; rt < 2; rt++){
    int rbase = m0 + w * 32 + rt * 16 + qd * 4;
    for (int ct = 0; ct < 8; ct++){
      int col = ct * 16 + l16;
      float bv = ldf(bias, col, fm);
      for (int rg = 0; rg < 4; rg++){
        int node = rbase + rg;
        if (node < NN) out[node * 128 + col] = acc[rt][ct][rg] + bv;
      }
    }
  }
}

// ---------------- edge kernel v2: B direct from L2, dst-dedup epilogue
__global__ __launch_bounds__(256) void k_edge2(const u16* __restrict__ h,
                                               const u16* __restrict__ wT,
                                               const u32* __restrict__ src_s,
                                               const u32* __restrict__ dst_s,
                                               const u32* __restrict__ relOff,
                                               const float* __restrict__ rcnt,
                                               float* __restrict__ out){
  __shared__ u16 As[32][128 + PADE];
  __shared__ float scL[32];
  __shared__ u32 dstL[32];
  int r = blockIdx.y;
  int tid = threadIdx.x;
  int w = tid >> 6, lane = tid & 63, qd = lane >> 4, l16 = lane & 15;
  u32 start = relOff[r], end = relOff[r + 1];
  int ntiles = (int)(end - start + 31) >> 5;
  int mt = w & 1, nb = (w >> 1) * 4;
  for (int t = blockIdx.x; t < ntiles; t += gridDim.x){
    u32 e0 = start + ((u32)t << 5);
    int mvalid = min(32, (int)(end - e0));
    __syncthreads();   // guard As/scL/dstL reuse
    {
      int row = tid >> 3, seg = tid & 7;
      uint4 v0 = make_uint4(0u,0u,0u,0u), v1 = v0;
      if (row < mvalid){
        u32 src = src_s[e0 + row];
        const u16* p = h + (size_t)src * 128 + seg * 16;
        v0 = *(const uint4*)(p);
        v1 = *(const uint4*)(p + 8);
      }
      *(uint4*)(&As[row][seg * 16]) = v0;
      *(uint4*)(&As[row][seg * 16 + 8]) = v1;
      if (tid < 32){
        if (tid < mvalid){
          u32 d = dst_s[e0 + tid];
          dstL[tid] = d;
          scL[tid] = rcnt[d * RR + r];
        } else { dstL[tid] = 0xFFFFFFFFu; scL[tid] = 0.f; }
      }
    }
    __syncthreads();
    f32x4 acc[4];
    for (int i = 0; i < 4; i++) acc[i] = (f32x4){0.f,0.f,0.f,0.f};
    for (int kk = 0; kk < 128; kk += 32){
      bf16x8 a = *(const bf16x8*)(&As[mt * 16 + l16][kk + qd * 8]);
      for (int i = 0; i < 4; i++){
        const u16* bp = wT + (size_t)((nb + i) * 16 + l16) * 1152 + r * 128 + kk + qd * 8;
        bf16x8 b = *(const bf16x8*)(bp);
        acc[i] = __builtin_amdgcn_mfma_f32_16x16x32_bf16(a, b, acc[i], 0, 0, 0);
      }
    }
    for (int i = 0; i < 4; i++){
      int col = (nb + i) * 16 + l16;
      float pend = 0.f; u32 pdst = 0xFFFFFFFFu;
      for (int rg = 0; rg < 4; rg++){
        int er = mt * 16 + qd * 4 + rg;
        if (er < mvalid){
          u32 d = dstL[er];
          float v = acc[i][rg] * scL[er];
          if (d == pdst) pend += v;
          else {
            if (pdst != 0xFFFFFFFFu) unsafeAtomicAdd(&out[(size_t)pdst * 128 + col], pend);
            pdst = d; pend = v;
          }
        }
      }
      if (pdst != 0xFFFFFFFFu) unsafeAtomicAdd(&out[(size_t)pdst * 128 + col], pend);
    }
  }
}

// ---------------- BatchNorm
__global__ void k_bnstats(const float* __restrict__ out, float* __restrict__ stats){
  __shared__ float sb[256], sb2[256];
  int tid = threadIdx.x;
  int col = tid & 127, half = tid >> 7;
  int r0 = blockIdx.x * 256;
  float s = 0.f, s2 = 0.f;
  for (int i = half; i < 256; i += 2){
    int n = r0 + i;
    if (n < NN){ float v = out[n * 128 + col]; s += v; s2 += v * v; }
  }
  sb[tid] = s; sb2[tid] = s2;
  __syncthreads();
  if (half == 0){
    unsafeAtomicAdd(&stats[col],       sb[col] + sb[col + 128]);
    unsafeAtomicAdd(&stats[128 + col], sb2[col] + sb2[col + 128]);
  }
}

__global__ void k_bnapply(const float* __restrict__ out, const float* __restrict__ stats,
                          const void* __restrict__ g, const void* __restrict__ beta,
                          u16* __restrict__ hout, const u32* md, u32* flags, u32 layerbit){
  u32 fm = md[0];
  int idx = (blockIdx.x * 256 + threadIdx.x) * 4;
  if (idx >= NN * 128) return;
  int col = idx & 127;
  float4 v = *(const float4*)(out + idx);
  float vv[4] = {v.x, v.y, v.z, v.w};
  bool bad = false;
  u16 o[4];
  for (int j = 0; j < 4; j++){
    int c = col + j;
    float mu = stats[c] * (1.0f / NN);
    float var = fmaxf(stats[128 + c] * (1.0f / NN) - mu * mu, 0.f);
    float sc = ldf(g, c, fm) * rsqrtf(var + 1e-5f);
    float sh = ldf(beta, c, fm) - mu * sc;
    float r = vv[j] * sc + sh;
    if (r != r || sc != sc){ bad = true; r = 0.f; }
    o[j] = f2bf(lrelu(r));
  }
  unsigned long long bal = __ballot(bad);
  if (bal && (threadIdx.x & 63) == 0) atomicOr(flags, layerbit);
  uint2 st;
  st.x = (u32)o[0] | ((u32)o[1] << 16);
  st.y = (u32)o[2] | ((u32)o[3] << 16);
  *(uint2*)(hout + idx) = st;
}

// ---------------- attention scores via MFMA
__global__ __launch_bounds__(256) void k_scores_mfma(const float* __restrict__ emb,
                                                     const u16* __restrict__ wext,
                                                     float* __restrict__ scores){
  __shared__ u16 As[128][136];
  int m0 = blockIdx.x * 128;
  int tid = threadIdx.x;
  int w = tid >> 6, lane = tid & 63, qd = lane >> 4, l16 = lane & 15;
  for (int it = 0; it < 16; it++){
    int lin = it * 1024 + tid * 4;
    int row = lin >> 7, c = lin & 127;
    int node = m0 + row;
    float4 v = make_float4(0.f,0.f,0.f,0.f);
    if (node < NN) v = *(const float4*)(emb + (size_t)node * 128 + c);
    uint2 st;
    st.x = (u32)f2bf(v.x) | ((u32)f2bf(v.y) << 16);
    st.y = (u32)f2bf(v.z) | ((u32)f2bf(v.w) << 16);
    *(uint2*)(&As[row][c]) = st;
  }
  __syncthreads();
  f32x4 acc[2][4];
  for (int i = 0; i < 2; i++) for (int j = 0; j < 4; j++) acc[i][j] = (f32x4){0.f,0.f,0.f,0.f};
  for (int k0 = 0; k0 < 4; k0++){
    bf16x8 a[2];
    a[0] = *(const bf16x8*)(&As[(w * 2) * 16 + l16][k0 * 32 + qd * 8]);
    a[1] = *(const bf16x8*)(&As[(w * 2 + 1) * 16 + l16][k0 * 32 + qd * 8]);
    for (int ct = 0; ct < 4; ct++){
      bf16x8 b = *(const bf16x8*)(wext + WX_A1T + (size_t)(ct * 16 + l16) * 128 + k0 * 32 + qd * 8);
      acc[0][ct] = __builtin_amdgcn_mfma_f32_16x16x32_bf16(a[0], b, acc[0][ct], 0, 0, 0);
      acc[1][ct] = __builtin_amdgcn_mfma_f32_16x16x32_bf16(a[1], b, acc[1][ct], 0, 0, 0);
    }
  }
  float a1v[4], a2v[4];
  for (int ct = 0; ct < 4; ct++){
    a1v[ct] = bf2f(wext[WX_a1 + ct * 16 + l16]);
    a2v[ct] = bf2f(wext[WX_A2 + ct * 16 + l16]);
  }
  float a2s = bf2f(wext[WX_a2s]);
  for (int rt = 0; rt < 2; rt++)
    for (int rg = 0; rg < 4; rg++){
      float s = 0.f;
      for (int ct = 0; ct < 4; ct++)
        s += lrelu(acc[rt][ct][rg] + a1v[ct]) * a2v[ct];
      s += __shfl_xor(s, 1); s += __shfl_xor(s, 2);
      s += __shfl_xor(s, 4); s += __shfl_xor(s, 8);
      int row = m0 + (w * 2 + rt) * 16 + qd * 4 + rg;
      if (l16 == 0 && row < NN) scores[row] = s + a2s;
    }
}

__device__ __forceinline__ u32 fmap(float f){
  union{u32 u; float f;} x; x.f = f;
  return (x.u & 0x80000000u) ? ~x.u : (x.u | 0x80000000u);
}
__device__ __forceinline__ float funmap(u32 m){
  union{u32 u; float f;} x;
  x.u = (m & 0x80000000u) ? (m ^ 0x80000000u) : ~m;
  return x.f;
}

__global__ void k_max(const float* __restrict__ scores, u32* smax){
  int gid = blockIdx.x * 256 + threadIdx.x;
  float m = -1e30f;
  for (int i = gid; i < NN; i += 256 * 128) m = fmaxf(m, scores[i]);
  for (int off = 32; off; off >>= 1) m = fmaxf(m, __shfl_down(m, off));
  if ((threadIdx.x & 63) == 0) atomicMax(smax, fmap(m));
}

__global__ void k_expsum(const float* __restrict__ scores, const u32* smax,
                         float* __restrict__ attnw, float* ssum, u32* flags){
  float mx = funmap(*smax);
  int gid = blockIdx.x * 256 + threadIdx.x;
  if (mx != mx){ if (gid == 0) atomicOr(flags, 32u); mx = 0.f; }
  float s = 0.f;
  bool bad = false;
  for (int i = gid; i < NN; i += 256 * 128){
    float e = __expf(scores[i] - mx);
    if (e != e){ bad = true; e = 0.f; }
    attnw[i] = e; s += e;
  }
  unsigned long long bal = __ballot(bad);
  if (bal && (threadIdx.x & 63) == 0) atomicOr(flags, 32u);
  for (int off = 32; off; off >>= 1) s += __shfl_down(s, off);
  if ((threadIdx.x & 63) == 0) unsafeAtomicAdd(ssum, s);
}

// ---------------- pooling
__global__ __launch_bounds__(128) void k_pool(const float* __restrict__ emb,
                                              const float* __restrict__ attnw,
                                              const float* __restrict__ ssum,
                                              const int* __restrict__ batch,
                                              float* __restrict__ gemb, u32* flags){
  int t = threadIdx.x;
  int n0 = blockIdx.x * 512;
  if (n0 >= NN) return;
  int n1 = min(n0 + 512, NN);
  float sv = *ssum;
  bool bad = !(sv > 0.f) || (sv != sv);
  if (bad && t == 0 && blockIdx.x == 0) atomicOr(flags, 64u);
  float rs = bad ? 0.f : 1.0f / sv;
  int cur = batch[n0];
  float acc = 0.f;
  for (int n = n0; n < n1; n++){
    int b = batch[n];
    if (b != cur){ unsafeAtomicAdd(&gemb[cur * 128 + t], acc * rs); acc = 0.f; cur = b; }
    acc += emb[n * 128 + t] * attnw[n];
  }
  unsafeAtomicAdd(&gemb[cur * 128 + t], acc * rs);
}

// ---------------- final combiner via MFMA + row L2 normalize
__global__ __launch_bounds__(256) void k_final_mfma(const float* __restrict__ emb,
                                                    const float* __restrict__ gemb,
                                                    const int* __restrict__ batch,
                                                    const u16* __restrict__ wext,
                                                    void* __restrict__ outp,
                                                    const u32* md){
  __shared__ u16 As[128][264];
  u16 (*Hs)[136] = (u16(*)[136])(&As[0][0]);
  u32 fm = md[0];
  int m0 = blockIdx.x * 128;
  int tid = threadIdx.x;
  int w = tid >> 6, lane = tid & 63, qd = lane >> 4, l16 = lane & 15;
  for (int it = 0; it < 32; it++){
    int lin = it * 1024 + tid * 4;
    int row = lin >> 8, c = lin & 255;
    int node = m0 + row;
    float4 v = make_float4(0.f,0.f,0.f,0.f);
    if (node < NN){
      if (c < 128) v = *(const float4*)(emb + (size_t)node * 128 + c);
      else { int g = batch[node]; v = *(const float4*)(gemb + (size_t)g * 128 + (c - 128)); }
    }
    uint2 st;
    st.x = (u32)f2bf(v.x) | ((u32)f2bf(v.y) << 16);
    st.y = (u32)f2bf(v.z) | ((u32)f2bf(v.w) << 16);
    *(uint2*)(&As[row][c]) = st;
  }
  __syncthreads();
  f32x4 acc[2][8];
  for (int i = 0; i < 2; i++) for (int j = 0; j < 8; j++) acc[i][j] = (f32x4){0.f,0.f,0.f,0.f};
  for (int k0 = 0; k0 < 8; k0++){
    bf16x8 a[2];
    a[0] = *(const bf16x8*)(&As[(w * 2) * 16 + l16][k0 * 32 + qd * 8]);
    a[1] = *(const bf16x8*)(&As[(w * 2 + 1) * 16 + l16][k0 * 32 + qd * 8]);
    for (int ct = 0; ct < 8; ct++){
      bf16x8 b = *(const bf16x8*)(wext + WX_C1T + (size_t)(ct * 16 + l16) * 256 + k0 * 32 + qd * 8);
      acc[0][ct] = __builtin_amdgcn_mfma_f32_16x16x32_bf16(a[0], b, acc[0][ct], 0, 0, 0);
      acc[1][ct] = __builtin_amdgcn_mfma_f32_16x16x32_bf16(a[1], b, acc[1][ct], 0, 0, 0);
    }
  }
  __syncthreads();
  for (int rt = 0; rt < 2; rt++)
    for (int ct = 0; ct < 8; ct++){
      float c1v = bf2f(wext[WX_c1 + ct * 16 + l16]);
      for (int rg = 0; rg < 4; rg++){
        int row = (w * 2 + rt) * 16 + qd * 4 + rg;
        Hs[row][ct * 16 + l16] = f2bf(lrelu(acc[rt][ct][rg] + c1v));
      }
    }
  __syncthreads();
  f32x4 acc2[2][8];
  for (int i = 0; i < 2; i++) for (int j = 0; j < 8; j++) acc2[i][j] = (f32x4){0.f,0.f,0.f,0.f};
  for (int k0 = 0; k0 < 4; k0++){
    bf16x8 a[2];
    a[0] = *(const bf16x8*)(&Hs[(w * 2) * 16 + l16][k0 * 32 + qd * 8]);
    a[1] = *(const bf16x8*)(&Hs[(w * 2 + 1) * 16 + l16][k0 * 32 + qd * 8]);
    for (int ct = 0; ct < 8; ct++){
      bf16x8 b = *(const bf16x8*)(wext + WX_C2T + (size_t)(ct * 16 + l16) * 128 + k0 * 32 + qd * 8);
      acc2[0][ct] = __builtin_amdgcn_mfma_f32_16x16x32_bf16(a[0], b, acc2[0][ct], 0, 0, 0);
      acc2[1][ct] = __builtin_amdgcn_mfma_f32_16x16x32_bf16(a[1], b, acc2[1][ct], 0, 0, 0);
    }
  }
  float c2v[8];
  for (int ct = 0; ct < 8; ct++) c2v[ct] = bf2f(wext[WX_c2 + ct * 16 + l16]);
  for (int rt = 0; rt < 2; rt++)
    for (int rg = 0; rg < 4; rg++){
      float ss = 0.f;
      for (int ct = 0; ct < 8; ct++){
        float o = acc2[rt][ct][rg] + c2v[ct];
        ss += o * o;
      }
      ss += __shfl_xor(ss, 1); ss += __shfl_xor(ss, 2);
      ss += __shfl_xor(ss, 4); ss += __shfl_xor(ss, 8);
      float sc = 1.0f / fmaxf(sqrtf(ss), 1e-12f);
      int row = m0 + (w * 2 + rt) * 16 + qd * 4 + rg;
      if (row < NN){
        if (fm){
          float* op = (float*)outp;
          for (int ct = 0; ct < 8; ct++)
            op[(size_t)row * 128 + ct * 16 + l16] = (acc2[rt][ct][rg] + c2v[ct]) * sc;
        } else {
          u16* op = (u16*)outp;
          for (int ct = 0; ct < 8; ct++)
            op[(size_t)row * 128 + ct * 16 + l16] = f2bf((acc2[rt][ct][rg] + c2v[ct]) * sc);
        }
      }
    }
}

// ---------------- diag sentinels
__global__ void k_diag(const u32* relOff, const u32* flags, const u32* md, void* outp){
  if (threadIdx.x != 0 || blockIdx.x != 0) return;
  u32 fm = md[0];
  u32 f = flags[0];
  if (relOff[RR] != (u32)EE) f |= 1u;
  for (int b = 0; b < 9; b++){
    if (f & (1u << b)){
      float s = (float)(131072 >> b);
      if (fm) ((float*)outp)[b] = s;
      else ((u16*)outp)[b] = f2bf(s);
    }
  }
}
__global__ void k_wsfail(u32* outp){ outp[0] = 0x43000000u; }

// ---------------- workspace layout (bytes)
constexpr size_t O_OUT   = 0;          // f32 N*128; pre-GEMM phase aliases: pairStart/cursor/blockSum/blockBase
constexpr size_t O_H     = 25600000;
constexpr size_t O_XBF   = 38400000;
constexpr size_t O_WCAT  = 51200000;
constexpr size_t O_WEXT  = 52084736;
constexpr size_t O_EI    = 52200448;
constexpr size_t O_ET    = 56200448;
constexpr size_t O_BAT   = 58200448;
constexpr size_t O_SRC   = 58400448;
constexpr size_t O_DST   = 60400448;
constexpr size_t O_CNT   = 62400448;
constexpr size_t O_RCNT  = 64000448;
constexpr size_t O_SCO   = 65600448;
constexpr size_t O_AW    = 65800448;
constexpr size_t O_GEMB  = 66000448;
constexpr size_t O_STATS = 66033216;
constexpr size_t O_MISC  = 66035264;
constexpr size_t WS_NEED = 66035520;

extern "C" void kernel_launch(void* const* d_in, const int* in_sizes, int n_in,
                              void* d_out, int out_size, void* d_ws, size_t ws_size,
                              hipStream_t stream) {
  const void* x     = d_in[0];
  const void* ei    = d_in[1];
  const void* et    = d_in[2];
  const void* batch = d_in[3];
  const void* W1 = d_in[4],  *r1 = d_in[5],  *b1 = d_in[6];
  const void* W2 = d_in[7],  *r2 = d_in[8],  *b2 = d_in[9];
  const void* W3 = d_in[10], *r3 = d_in[11], *b3 = d_in[12];
  const void* g1 = d_in[13], *be1 = d_in[14];
  const void* g2 = d_in[15], *be2 = d_in[16];
  const void* A1 = d_in[17], *a1 = d_in[18];
  const void* A2 = d_in[19], *a2 = d_in[20];
  const void* C1 = d_in[21], *c1 = d_in[22];
  const void* C2 = d_in[23], *c2 = d_in[24];

  if (ws_size < WS_NEED){ k_wsfail<<<1, 1, 0, stream>>>((u32*)d_out); return; }
  char* ws = (char*)d_ws;
  float* out   = (float*)(ws + O_OUT);
  u16*   hbuf  = (u16*)(ws + O_H);
  u16*   xbf   = (u16*)(ws + O_XBF);
  u16*   wcat  = (u16*)(ws + O_WCAT);
  u16*   wext  = (u16*)(ws + O_WEXT);
  int*   ei_c  = (int*)(ws + O_EI);
  int*   et_c  = (int*)(ws + O_ET);
  int*   bat_c = (int*)(ws + O_BAT);
  u32*   src_s = (u32*)(ws + O_SRC);
  u32*   dst_s = (u32*)(ws + O_DST);
  u32*   cnt   = (u32*)(ws + O_CNT);
  float* rcnt  = (float*)(ws + O_RCNT);
  float* sco   = (float*)(ws + O_SCO);
  float* aw    = (float*)(ws + O_AW);
  float* gemb  = (float*)(ws + O_GEMB);
  float* stats = (float*)(ws + O_STATS);
  u32*   misc  = (u32*)(ws + O_MISC);
  // pre-GEMM aliases inside the O_OUT region (out not yet live):
  u32* pairStart = (u32*)(ws + O_OUT);                 // 400K u32 = 1.6 MB
  u32* cursor    = (u32*)(ws + O_OUT + 1600000);       // 400K u32 = 1.6 MB
  u32* blockSum  = (u32*)(ws + O_OUT + 3200000);       // 782 u32
  u32* blockBase = (u32*)(ws + O_OUT + 3204096);       // 782 u32
  u32* relOff = misc + 16;   // 16..24
  u32* smax = misc + 25;
  float* ssum = (float*)(misc + 26);
  u32* flags = misc + 27;
  u32* md = misc + 28;       // md[0]=fmode(f32?), md[1]=imode(int64?)

  hipMemsetAsync(ws + O_CNT, 0, 1600000, stream);
  hipMemsetAsync(ws + O_GEMB, 0, 32768 + 2048 + 256, stream);

  k_fdetect<<<1, 256, 0, stream>>>(x, md);
  k_idetect<<<1, 256, 0, stream>>>(et, md);
  k_icvt<<<6055, 256, 0, stream>>>(ei, et, batch, ei_c, et_c, bat_c, md);
  k_xcvt<<<6250, 256, 0, stream>>>(x, xbf, md, flags);
  k_wcat<<<1728, 256, 0, stream>>>(W1, r1, W2, r2, W3, r3, wcat, md, flags);
  k_wext<<<227, 256, 0, stream>>>(A1, a1, A2, a2, C1, c1, C2, c2, wext, md);

  k_count3<<<(EE + 255) / 256, 256, 0, stream>>>(ei_c, et_c, cnt);
  k_pairA<<<PAIR_B, 256, 0, stream>>>(cnt, blockSum);
  k_pairB<<<1, 64, 0, stream>>>(blockSum, blockBase);
  k_pairC<<<PAIR_B, 256, 0, stream>>>(cnt, blockBase, pairStart, cursor);
  k_reloff<<<1, 64, 0, stream>>>(pairStart, relOff);
  k_sort3<<<(EE + 255) / 256, 256, 0, stream>>>(ei_c, et_c, pairStart, cursor, src_s, dst_s);
  k_rcnt<<<(NN * RR + 255) / 256, 256, 0, stream>>>(cnt, rcnt);

  const void* bias[3] = {b1, b2, b3};
  const void* gam[2] = {g1, g2};
  const void* bet[2] = {be1, be2};
  const u16* hin = xbf;
  for (int L = 0; L < 3; L++){
    const u16* wT = wcat + (size_t)L * 128 * 1152;
    k_gemm_root<<<391, 256, 0, stream>>>(hin, wT, bias[L], out, md);
    k_edge2<<<dim3(192, 8), 256, 0, stream>>>(hin, wT, src_s, dst_s, relOff, rcnt, out);
    if (L < 2){
      k_bnstats<<<196, 256, 0, stream>>>(out, stats + L * 256);
      k_bnapply<<<6250, 256, 0, stream>>>(out, stats + L * 256, gam[L], bet[L], hbuf, md, flags, 4u << L);
      hin = hbuf;
    }
  }
  k_scores_mfma<<<391, 256, 0, stream>>>(out, wext, sco);
  k_max<<<128, 256, 0, stream>>>(sco, smax);
  k_expsum<<<128, 256, 0, stream>>>(sco, smax, aw, ssum, flags);
  k_pool<<<98, 128, 0, stream>>>(out, aw, ssum, bat_c, gemb, flags);
  k_final_mfma<<<391, 256, 0, stream>>>(out, gemb, bat_c, wext, d_out, md);
  k_diag<<<1, 64, 0, stream>>>(relOff, flags, md, d_out);
}

// Round 6
// 1011.812 us; speedup vs baseline: 5.1978x; 1.0858x over previous
//
#include <hip/hip_runtime.h>
#include <hip/hip_bf16.h>

typedef unsigned int u32;
typedef unsigned short u16;
typedef __bf16 bf16_t;
typedef bf16_t bf16x8 __attribute__((ext_vector_type(8)));
typedef float f32x4 __attribute__((ext_vector_type(4)));

constexpr int NN = 50000;
constexpr int EE = 500000;
constexpr int RR = 8;
constexpr int NKEY = RR * NN;               // 400000
constexpr int PAIR_B = (NKEY + 511) / 512;  // 782

// wext element offsets (bf16 elems)
constexpr int WX_A1T = 0;       // [64][128]
constexpr int WX_C1T = 8192;    // [128][256]
constexpr int WX_C2T = 40960;   // [128][128]
constexpr int WX_A2  = 57344;   // [64]
constexpr int WX_a1  = 57408;   // [64]
constexpr int WX_c1  = 57472;   // [128]
constexpr int WX_c2  = 57600;   // [128]
constexpr int WX_a2s = 57728;   // [1]
constexpr int WX_TOT = 57729;

__device__ __forceinline__ float bf2f(u32 v){
  union { u32 u; float f; } x; x.u = (v & 0xFFFFu) << 16; return x.f;
}
__device__ __forceinline__ u16 f2bf(float f){
  union { u32 u; float f; } x; x.f = f;
  u32 r = x.u + 0x7FFFu + ((x.u >> 16) & 1u);
  return (u16)(r >> 16);
}
__device__ __forceinline__ float lrelu(float x){ return x > 0.f ? x : 0.1f * x; }
__device__ __forceinline__ float ldf(const void* p, int i, u32 fm){
  return fm ? ((const float*)p)[i] : bf2f(((const u16*)p)[i]);
}

// ---------------- dtype detectors ----------------
__global__ void k_fdetect(const void* x, u32* md){
  __shared__ u32 c;
  if (threadIdx.x == 0) c = 0;
  __syncthreads();
  const u16* p = (const u16*)x;
  u32 loc = 0;
  for (int j = 0; j < 16; j++){
    u16 v = p[threadIdx.x * 16 + j];
    u32 e = (v >> 7) & 0xFF;
    if (e >= 0xFD) loc++;
  }
  atomicAdd(&c, loc);
  __syncthreads();
  if (threadIdx.x == 0) md[0] = (c >= 4) ? 1u : 0u;
}
__global__ void k_idetect(const void* et, u32* md){
  __shared__ u32 c;
  if (threadIdx.x == 0) c = 0;
  __syncthreads();
  const int* p = (const int*)et;
  u32 loc = 0;
  for (int j = 0; j < 8; j++){
    int idx = 2 * (threadIdx.x * 8 + j) + 1;
    if (p[idx] != 0) loc++;
  }
  atomicAdd(&c, loc);
  __syncthreads();
  if (threadIdx.x == 0) md[1] = (c == 0) ? 1u : 0u;
}

// ---------------- int conversion -> int32 ws copies
__global__ void k_icvt(const void* ei, const void* et, const void* bat,
                       int* ei_c, int* et_c, int* bat_c, const u32* md){
  u32 im = md[1];
  int i = blockIdx.x * 256 + threadIdx.x;
  if (i < 2 * EE){
    const int* p = (const int*)ei;
    ei_c[i] = im ? p[2 * i] : p[i];
  } else if (i < 3 * EE){
    int j = i - 2 * EE;
    const int* p = (const int*)et;
    et_c[j] = im ? p[2 * j] : p[j];
  } else if (i < 3 * EE + NN){
    int j = i - 3 * EE;
    const int* p = (const int*)bat;
    bat_c[j] = im ? p[2 * j] : p[j];
  }
}

// ---------------- x conversion -> bf16 ws copy (+NaN flag bit1)
__global__ void k_xcvt(const void* x, u16* xb, const u32* md, u32* flags){
  u32 fm = md[0];
  int i4 = (blockIdx.x * 256 + threadIdx.x) * 4;
  if (i4 >= NN * 128) return;
  float v[4];
  if (fm){
    float4 f = *(const float4*)((const float*)x + i4);
    v[0]=f.x; v[1]=f.y; v[2]=f.z; v[3]=f.w;
  } else {
    uint2 u = *(const uint2*)((const u16*)x + i4);
    v[0]=bf2f(u.x); v[1]=bf2f(u.x>>16); v[2]=bf2f(u.y); v[3]=bf2f(u.y>>16);
  }
  bool bad = false;
  u16 o[4];
  for (int j = 0; j < 4; j++){
    if (v[j] != v[j]){ bad = true; v[j] = 0.f; }
    o[j] = f2bf(v[j]);
  }
  unsigned long long bal = __ballot(bad);
  if (bal && (threadIdx.x & 63) == 0) atomicOr(flags, 2u);
  uint2 st;
  st.x = (u32)o[0] | ((u32)o[1] << 16);
  st.y = (u32)o[2] | ((u32)o[3] << 16);
  *(uint2*)(xb + i4) = st;
}

// ---------------- weight transpose: wcatT[L][n][k]; k<1024 -> W[L][k][n], else root[k-1024][n]
__global__ void k_wcat(const void* W1, const void* r1, const void* W2, const void* r2,
                       const void* W3, const void* r3, u16* wcatT, const u32* md, u32* flags){
  u32 fm = md[0];
  int idx = blockIdx.x * 256 + threadIdx.x;
  if (idx >= 3 * 128 * 1152) return;
  int L = idx / (128 * 1152);
  int rem = idx % (128 * 1152);
  int n = rem / 1152, k = rem % 1152;
  const void* W  = (L == 0) ? W1 : ((L == 1) ? W2 : W3);
  const void* rt = (L == 0) ? r1 : ((L == 1) ? r2 : r3);
  float v = (k < 1024) ? ldf(W, k * 128 + n, fm) : ldf(rt, (k - 1024) * 128 + n, fm);
  if (v != v){ v = 0.f; atomicOr(flags, 2u); }
  wcatT[idx] = f2bf(v);
}

// ---------------- small-MLP weight prep
__global__ void k_wext(const void* A1, const void* a1, const void* A2, const void* a2,
                       const void* C1, const void* c1, const void* C2, const void* c2,
                       u16* wext, const u32* md){
  u32 fm = md[0];
  int idx = blockIdx.x * 256 + threadIdx.x;
  if (idx >= WX_TOT) return;
  float v;
  if (idx < WX_C1T){
    int n = idx >> 7, k = idx & 127;
    v = ldf(A1, k * 64 + n, fm);
  } else if (idx < WX_C2T){
    int j = idx - WX_C1T; int n = j >> 8, k = j & 255;
    v = ldf(C1, k * 128 + n, fm);
  } else if (idx < WX_A2){
    int j = idx - WX_C2T; int n = j >> 7, k = j & 127;
    v = ldf(C2, k * 128 + n, fm);
  } else if (idx < WX_a1){ v = ldf(A2, idx - WX_A2, fm); }
  else if (idx < WX_c1){ v = ldf(a1, idx - WX_a1, fm); }
  else if (idx < WX_c2){ v = ldf(c1, idx - WX_c1, fm); }
  else if (idx < WX_a2s){ v = ldf(c2, idx - WX_c2, fm); }
  else { v = ldf(a2, 0, fm); }
  wext[idx] = f2bf(v);
}

// ---------------- (rel,dst) counting sort ----------------
__global__ void k_count3(const int* __restrict__ ei, const int* __restrict__ et, u32* __restrict__ cnt){
  int e = blockIdx.x * 256 + threadIdx.x;
  if (e >= EE) return;
  atomicAdd(&cnt[ei[EE + e] * RR + et[e]], 1u);
}
__global__ void k_pairA(const u32* __restrict__ cnt, u32* __restrict__ blockSum){
  __shared__ u32 sd[256];
  int b = blockIdx.x, t = threadIdx.x;
  u32 s = 0;
  for (int j = 0; j < 2; j++){
    int key = b * 512 + t * 2 + j;
    if (key < NKEY){ int r = key / NN, d = key % NN; s += cnt[d * RR + r]; }
  }
  sd[t] = s; __syncthreads();
  for (int off = 128; off; off >>= 1){ if (t < off) sd[t] += sd[t + off]; __syncthreads(); }
  if (t == 0) blockSum[b] = sd[0];
}
__global__ void k_pairB(const u32* __restrict__ blockSum, u32* __restrict__ blockBase){
  int lane = threadIdx.x;   // 64
  u32 loc[13]; u32 s = 0;
  for (int j = 0; j < 13; j++){
    int b = lane * 13 + j;
    u32 v = (b < PAIR_B) ? blockSum[b] : 0u;
    loc[j] = s; s += v;
  }
  u32 tot = s;
  for (int off = 1; off < 64; off <<= 1){
    u32 x = __shfl_up(tot, off);
    if (lane >= off) tot += x;
  }
  u32 excl = tot - s;
  for (int j = 0; j < 13; j++){
    int b = lane * 13 + j;
    if (b < PAIR_B) blockBase[b] = excl + loc[j];
  }
}
__global__ void k_pairC(const u32* __restrict__ cnt, const u32* __restrict__ blockBase,
                        u32* __restrict__ pairStart, u32* __restrict__ cursor){
  __shared__ u32 sd[256];
  int b = blockIdx.x, t = threadIdx.x;
  int k0 = b * 512 + t * 2;
  u32 v0 = 0, v1 = 0;
  if (k0 < NKEY){ int r = k0 / NN, d = k0 % NN; v0 = cnt[d * RR + r]; }
  if (k0 + 1 < NKEY){ int r = (k0 + 1) / NN, d = (k0 + 1) % NN; v1 = cnt[d * RR + r]; }
  sd[t] = v0 + v1; __syncthreads();
  for (int off = 1; off < 256; off <<= 1){
    u32 x = (t >= off) ? sd[t - off] : 0u;
    __syncthreads();
    sd[t] += x;
    __syncthreads();
  }
  u32 excl = sd[t] - (v0 + v1);
  u32 base = blockBase[b] + excl;
  if (k0 < NKEY){ pairStart[k0] = base; cursor[k0] = 0u; }
  if (k0 + 1 < NKEY){ pairStart[k0 + 1] = base + v0; cursor[k0 + 1] = 0u; }
}
__global__ void k_reloff(u32* __restrict__ pairStart, u32* __restrict__ relOff){
  int t = threadIdx.x;
  if (t < RR) relOff[t] = pairStart[t * NN];
  if (t == RR){ relOff[RR] = (u32)EE; pairStart[NKEY] = (u32)EE; }
}
__global__ void k_sort3(const int* __restrict__ ei, const int* __restrict__ et,
                        const u32* __restrict__ pairStart, u32* __restrict__ cursor,
                        u32* __restrict__ src_s){
  int e = blockIdx.x * 256 + threadIdx.x;
  if (e >= EE) return;
  int r = et[e], d = ei[EE + e];
  u32 key = (u32)r * NN + (u32)d;
  u32 p = pairStart[key] + atomicAdd(&cursor[key], 1u);
  src_s[p] = (u32)ei[e];
}

// ---------------- segment-sum aggregation: agg[d][r*128..] = mean h[src] over key segment
// one wave per (r,d) key; lanes cover 128 dims (2 each); contiguous segment, no atomics
__global__ __launch_bounds__(256) void k_agg(const u16* __restrict__ h,
                                             const u32* __restrict__ pairStart,
                                             const u32* __restrict__ src_s,
                                             u16* __restrict__ agg){
  int wid = blockIdx.x * 4 + (threadIdx.x >> 6);
  if (wid >= NKEY) return;
  int lane = threadIdx.x & 63;
  u32 s = pairStart[wid], e = pairStart[wid + 1];
  int r = wid / NN, d = wid - r * NN;
  float a0 = 0.f, a1 = 0.f;
  for (u32 j = s; j < e; j++){
    u32 src = src_s[j];
    u32 v = *(const u32*)(h + (size_t)src * 128 + lane * 2);
    a0 += bf2f(v); a1 += bf2f(v >> 16);
  }
  int c = (int)(e - s);
  float sc = 1.0f / (float)max(c, 1);
  u32 st = (u32)f2bf(a0 * sc) | ((u32)f2bf(a1 * sc) << 16);
  *(u32*)(agg + (size_t)d * 1024 + r * 128 + lane * 2) = st;
}

// ---------------- big GEMM: out[N,128] = [agg | h] (K=1152) @ wcatT + bias
#define PADE 8
__global__ __launch_bounds__(256) void k_gemm_big(const u16* __restrict__ h,
                                                  const u16* __restrict__ agg,
                                                  const u16* __restrict__ wT,
                                                  const void* __restrict__ bias,
                                                  float* __restrict__ out, const u32* md){
  __shared__ u16 As[128][64 + PADE];
  __shared__ u16 Bs[128][64 + PADE];
  u32 fm = md[0];
  int m0 = blockIdx.x * 128;
  int tid = threadIdx.x;
  int w = tid >> 6, lane = tid & 63, qd = lane >> 4, l16 = lane & 15;
  f32x4 acc[2][8];
  for (int i = 0; i < 2; i++) for (int j = 0; j < 8; j++) acc[i][j] = (f32x4){0.f,0.f,0.f,0.f};
  for (int k0 = 0; k0 < 1152; k0 += 64){
    __syncthreads();
    for (int it = 0; it < 4; it++){
      int lin = it * 2048 + tid * 8;
      int row = lin >> 6, kl = lin & 63;
      int node = m0 + row;
      int k = k0 + kl;
      uint4 v = make_uint4(0u,0u,0u,0u);
      if (node < NN){
        if (k < 1024) v = *(const uint4*)(agg + (size_t)node * 1024 + k);
        else v = *(const uint4*)(h + (size_t)node * 128 + (k - 1024));
      }
      *(uint4*)(&As[row][kl]) = v;
      uint4 b = *(const uint4*)(wT + (size_t)row * 1152 + k0 + kl);
      *(uint4*)(&Bs[row][kl]) = b;
    }
    __syncthreads();
    for (int kk = 0; kk < 64; kk += 32){
      bf16x8 a[2], bf[8];
      for (int rt = 0; rt < 2; rt++) a[rt] = *(const bf16x8*)(&As[w * 32 + rt * 16 + l16][kk + qd * 8]);
      for (int ct = 0; ct < 8; ct++) bf[ct] = *(const bf16x8*)(&Bs[ct * 16 + l16][kk + qd * 8]);
      for (int rt = 0; rt < 2; rt++)
        for (int ct = 0; ct < 8; ct++)
          acc[rt][ct] = __builtin_amdgcn_mfma_f32_16x16x32_bf16(a[rt], bf[ct], acc[rt][ct], 0, 0, 0);
    }
  }
  for (int rt = 0; rt < 2; rt++){
    int rbase = m0 + w * 32 + rt * 16 + qd * 4;
    for (int ct = 0; ct < 8; ct++){
      int col = ct * 16 + l16;
      float bv = ldf(bias, col, fm);
      for (int rg = 0; rg < 4; rg++){
        int node = rbase + rg;
        if (node < NN) out[node * 128 + col] = acc[rt][ct][rg] + bv;
      }
    }
  }
}

// ---------------- BatchNorm
__global__ void k_bnstats(const float* __restrict__ out, float* __restrict__ stats){
  __shared__ float sb[256], sb2[256];
  int tid = threadIdx.x;
  int col = tid & 127, half = tid >> 7;
  int r0 = blockIdx.x * 256;
  float s = 0.f, s2 = 0.f;
  for (int i = half; i < 256; i += 2){
    int n = r0 + i;
    if (n < NN){ float v = out[n * 128 + col]; s += v; s2 += v * v; }
  }
  sb[tid] = s; sb2[tid] = s2;
  __syncthreads();
  if (half == 0){
    unsafeAtomicAdd(&stats[col],       sb[col] + sb[col + 128]);
    unsafeAtomicAdd(&stats[128 + col], sb2[col] + sb2[col + 128]);
  }
}

__global__ void k_bnapply(const float* __restrict__ out, const float* __restrict__ stats,
                          const void* __restrict__ g, const void* __restrict__ beta,
                          u16* __restrict__ hout, const u32* md, u32* flags, u32 layerbit){
  u32 fm = md[0];
  int idx = (blockIdx.x * 256 + threadIdx.x) * 4;
  if (idx >= NN * 128) return;
  int col = idx & 127;
  float4 v = *(const float4*)(out + idx);
  float vv[4] = {v.x, v.y, v.z, v.w};
  bool bad = false;
  u16 o[4];
  for (int j = 0; j < 4; j++){
    int c = col + j;
    float mu = stats[c] * (1.0f / NN);
    float var = fmaxf(stats[128 + c] * (1.0f / NN) - mu * mu, 0.f);
    float sc = ldf(g, c, fm) * rsqrtf(var + 1e-5f);
    float sh = ldf(beta, c, fm) - mu * sc;
    float r = vv[j] * sc + sh;
    if (r != r || sc != sc){ bad = true; r = 0.f; }
    o[j] = f2bf(lrelu(r));
  }
  unsigned long long bal = __ballot(bad);
  if (bal && (threadIdx.x & 63) == 0) atomicOr(flags, layerbit);
  uint2 st;
  st.x = (u32)o[0] | ((u32)o[1] << 16);
  st.y = (u32)o[2] | ((u32)o[3] << 16);
  *(uint2*)(hout + idx) = st;
}

// ---------------- attention scores via MFMA
__global__ __launch_bounds__(256) void k_scores_mfma(const float* __restrict__ emb,
                                                     const u16* __restrict__ wext,
                                                     float* __restrict__ scores){
  __shared__ u16 As[128][136];
  int m0 = blockIdx.x * 128;
  int tid = threadIdx.x;
  int w = tid >> 6, lane = tid & 63, qd = lane >> 4, l16 = lane & 15;
  for (int it = 0; it < 16; it++){
    int lin = it * 1024 + tid * 4;
    int row = lin >> 7, c = lin & 127;
    int node = m0 + row;
    float4 v = make_float4(0.f,0.f,0.f,0.f);
    if (node < NN) v = *(const float4*)(emb + (size_t)node * 128 + c);
    uint2 st;
    st.x = (u32)f2bf(v.x) | ((u32)f2bf(v.y) << 16);
    st.y = (u32)f2bf(v.z) | ((u32)f2bf(v.w) << 16);
    *(uint2*)(&As[row][c]) = st;
  }
  __syncthreads();
  f32x4 acc[2][4];
  for (int i = 0; i < 2; i++) for (int j = 0; j < 4; j++) acc[i][j] = (f32x4){0.f,0.f,0.f,0.f};
  for (int k0 = 0; k0 < 4; k0++){
    bf16x8 a[2];
    a[0] = *(const bf16x8*)(&As[(w * 2) * 16 + l16][k0 * 32 + qd * 8]);
    a[1] = *(const bf16x8*)(&As[(w * 2 + 1) * 16 + l16][k0 * 32 + qd * 8]);
    for (int ct = 0; ct < 4; ct++){
      bf16x8 b = *(const bf16x8*)(wext + WX_A1T + (size_t)(ct * 16 + l16) * 128 + k0 * 32 + qd * 8);
      acc[0][ct] = __builtin_amdgcn_mfma_f32_16x16x32_bf16(a[0], b, acc[0][ct], 0, 0, 0);
      acc[1][ct] = __builtin_amdgcn_mfma_f32_16x16x32_bf16(a[1], b, acc[1][ct], 0, 0, 0);
    }
  }
  float a1v[4], a2v[4];
  for (int ct = 0; ct < 4; ct++){
    a1v[ct] = bf2f(wext[WX_a1 + ct * 16 + l16]);
    a2v[ct] = bf2f(wext[WX_A2 + ct * 16 + l16]);
  }
  float a2s = bf2f(wext[WX_a2s]);
  for (int rt = 0; rt < 2; rt++)
    for (int rg = 0; rg < 4; rg++){
      float s = 0.f;
      for (int ct = 0; ct < 4; ct++)
        s += lrelu(acc[rt][ct][rg] + a1v[ct]) * a2v[ct];
      s += __shfl_xor(s, 1); s += __shfl_xor(s, 2);
      s += __shfl_xor(s, 4); s += __shfl_xor(s, 8);
      int row = m0 + (w * 2 + rt) * 16 + qd * 4 + rg;
      if (l16 == 0 && row < NN) scores[row] = s + a2s;
    }
}

__device__ __forceinline__ u32 fmap(float f){
  union{u32 u; float f;} x; x.f = f;
  return (x.u & 0x80000000u) ? ~x.u : (x.u | 0x80000000u);
}
__device__ __forceinline__ float funmap(u32 m){
  union{u32 u; float f;} x;
  x.u = (m & 0x80000000u) ? (m ^ 0x80000000u) : ~m;
  return x.f;
}

__global__ void k_max(const float* __restrict__ scores, u32* smax){
  int gid = blockIdx.x * 256 + threadIdx.x;
  float m = -1e30f;
  for (int i = gid; i < NN; i += 256 * 128) m = fmaxf(m, scores[i]);
  for (int off = 32; off; off >>= 1) m = fmaxf(m, __shfl_down(m, off));
  if ((threadIdx.x & 63) == 0) atomicMax(smax, fmap(m));
}

__global__ void k_expsum(const float* __restrict__ scores, const u32* smax,
                         float* __restrict__ attnw, float* ssum, u32* flags){
  float mx = funmap(*smax);
  int gid = blockIdx.x * 256 + threadIdx.x;
  if (mx != mx){ if (gid == 0) atomicOr(flags, 32u); mx = 0.f; }
  float s = 0.f;
  bool bad = false;
  for (int i = gid; i < NN; i += 256 * 128){
    float e = __expf(scores[i] - mx);
    if (e != e){ bad = true; e = 0.f; }
    attnw[i] = e; s += e;
  }
  unsigned long long bal = __ballot(bad);
  if (bal && (threadIdx.x & 63) == 0) atomicOr(flags, 32u);
  for (int off = 32; off; off >>= 1) s += __shfl_down(s, off);
  if ((threadIdx.x & 63) == 0) unsafeAtomicAdd(ssum, s);
}

// ---------------- pooling
__global__ __launch_bounds__(128) void k_pool(const float* __restrict__ emb,
                                              const float* __restrict__ attnw,
                                              const float* __restrict__ ssum,
                                              const int* __restrict__ batch,
                                              float* __restrict__ gemb, u32* flags){
  int t = threadIdx.x;
  int n0 = blockIdx.x * 512;
  if (n0 >= NN) return;
  int n1 = min(n0 + 512, NN);
  float sv = *ssum;
  bool bad = !(sv > 0.f) || (sv != sv);
  if (bad && t == 0 && blockIdx.x == 0) atomicOr(flags, 64u);
  float rs = bad ? 0.f : 1.0f / sv;
  int cur = batch[n0];
  float acc = 0.f;
  for (int n = n0; n < n1; n++){
    int b = batch[n];
    if (b != cur){ unsafeAtomicAdd(&gemb[cur * 128 + t], acc * rs); acc = 0.f; cur = b; }
    acc += emb[n * 128 + t] * attnw[n];
  }
  unsafeAtomicAdd(&gemb[cur * 128 + t], acc * rs);
}

// ---------------- final combiner via MFMA + row L2 normalize
__global__ __launch_bounds__(256) void k_final_mfma(const float* __restrict__ emb,
                                                    const float* __restrict__ gemb,
                                                    const int* __restrict__ batch,
                                                    const u16* __restrict__ wext,
                                                    void* __restrict__ outp,
                                                    const u32* md){
  __shared__ u16 As[128][264];
  u16 (*Hs)[136] = (u16(*)[136])(&As[0][0]);
  u32 fm = md[0];
  int m0 = blockIdx.x * 128;
  int tid = threadIdx.x;
  int w = tid >> 6, lane = tid & 63, qd = lane >> 4, l16 = lane & 15;
  for (int it = 0; it < 32; it++){
    int lin = it * 1024 + tid * 4;
    int row = lin >> 8, c = lin & 255;
    int node = m0 + row;
    float4 v = make_float4(0.f,0.f,0.f,0.f);
    if (node < NN){
      if (c < 128) v = *(const float4*)(emb + (size_t)node * 128 + c);
      else { int g = batch[node]; v = *(const float4*)(gemb + (size_t)g * 128 + (c - 128)); }
    }
    uint2 st;
    st.x = (u32)f2bf(v.x) | ((u32)f2bf(v.y) << 16);
    st.y = (u32)f2bf(v.z) | ((u32)f2bf(v.w) << 16);
    *(uint2*)(&As[row][c]) = st;
  }
  __syncthreads();
  f32x4 acc[2][8];
  for (int i = 0; i < 2; i++) for (int j = 0; j < 8; j++) acc[i][j] = (f32x4){0.f,0.f,0.f,0.f};
  for (int k0 = 0; k0 < 8; k0++){
    bf16x8 a[2];
    a[0] = *(const bf16x8*)(&As[(w * 2) * 16 + l16][k0 * 32 + qd * 8]);
    a[1] = *(const bf16x8*)(&As[(w * 2 + 1) * 16 + l16][k0 * 32 + qd * 8]);
    for (int ct = 0; ct < 8; ct++){
      bf16x8 b = *(const bf16x8*)(wext + WX_C1T + (size_t)(ct * 16 + l16) * 256 + k0 * 32 + qd * 8);
      acc[0][ct] = __builtin_amdgcn_mfma_f32_16x16x32_bf16(a[0], b, acc[0][ct], 0, 0, 0);
      acc[1][ct] = __builtin_amdgcn_mfma_f32_16x16x32_bf16(a[1], b, acc[1][ct], 0, 0, 0);
    }
  }
  __syncthreads();
  for (int rt = 0; rt < 2; rt++)
    for (int ct = 0; ct < 8; ct++){
      float c1v = bf2f(wext[WX_c1 + ct * 16 + l16]);
      for (int rg = 0; rg < 4; rg++){
        int row = (w * 2 + rt) * 16 + qd * 4 + rg;
        Hs[row][ct * 16 + l16] = f2bf(lrelu(acc[rt][ct][rg] + c1v));
      }
    }
  __syncthreads();
  f32x4 acc2[2][8];
  for (int i = 0; i < 2; i++) for (int j = 0; j < 8; j++) acc2[i][j] = (f32x4){0.f,0.f,0.f,0.f};
  for (int k0 = 0; k0 < 4; k0++){
    bf16x8 a[2];
    a[0] = *(const bf16x8*)(&Hs[(w * 2) * 16 + l16][k0 * 32 + qd * 8]);
    a[1] = *(const bf16x8*)(&Hs[(w * 2 + 1) * 16 + l16][k0 * 32 + qd * 8]);
    for (int ct = 0; ct < 8; ct++){
      bf16x8 b = *(const bf16x8*)(wext + WX_C2T + (size_t)(ct * 16 + l16) * 128 + k0 * 32 + qd * 8);
      acc2[0][ct] = __builtin_amdgcn_mfma_f32_16x16x32_bf16(a[0], b, acc2[0][ct], 0, 0, 0);
      acc2[1][ct] = __builtin_amdgcn_mfma_f32_16x16x32_bf16(a[1], b, acc2[1][ct], 0, 0, 0);
    }
  }
  float c2v[8];
  for (int ct = 0; ct < 8; ct++) c2v[ct] = bf2f(wext[WX_c2 + ct * 16 + l16]);
  for (int rt = 0; rt < 2; rt++)
    for (int rg = 0; rg < 4; rg++){
      float ss = 0.f;
      for (int ct = 0; ct < 8; ct++){
        float o = acc2[rt][ct][rg] + c2v[ct];
        ss += o * o;
      }
      ss += __shfl_xor(ss, 1); ss += __shfl_xor(ss, 2);
      ss += __shfl_xor(ss, 4); ss += __shfl_xor(ss, 8);
      float sc = 1.0f / fmaxf(sqrtf(ss), 1e-12f);
      int row = m0 + (w * 2 + rt) * 16 + qd * 4 + rg;
      if (row < NN){
        if (fm){
          float* op = (float*)outp;
          for (int ct = 0; ct < 8; ct++)
            op[(size_t)row * 128 + ct * 16 + l16] = (acc2[rt][ct][rg] + c2v[ct]) * sc;
        } else {
          u16* op = (u16*)outp;
          for (int ct = 0; ct < 8; ct++)
            op[(size_t)row * 128 + ct * 16 + l16] = f2bf((acc2[rt][ct][rg] + c2v[ct]) * sc);
        }
      }
    }
}

// ---------------- diag sentinels
__global__ void k_diag(const u32* relOff, const u32* flags, const u32* md, void* outp){
  if (threadIdx.x != 0 || blockIdx.x != 0) return;
  u32 fm = md[0];
  u32 f = flags[0];
  if (relOff[RR] != (u32)EE) f |= 1u;
  for (int b = 0; b < 9; b++){
    if (f & (1u << b)){
      float s = (float)(131072 >> b);
      if (fm) ((float*)outp)[b] = s;
      else ((u16*)outp)[b] = f2bf(s);
    }
  }
}
__global__ void k_wsfail(u32* outp){ outp[0] = 0x43000000u; }

// ---------------- workspace layout (bytes)
constexpr size_t O_OUT   = 0;          // f32 N*128; pre-GEMM aliases: cursor/blockSum/blockBase
constexpr size_t O_H     = 25600000;
constexpr size_t O_XBF   = 38400000;
constexpr size_t O_WCAT  = 51200000;
constexpr size_t O_WEXT  = 52084736;
constexpr size_t O_EI    = 52200448;
constexpr size_t O_ET    = 56200448;
constexpr size_t O_BAT   = 58200448;
constexpr size_t O_SRC   = 58400448;   // 2 MB (src_s)
constexpr size_t O_PST   = 60400448;   // pairStart: (NKEY+1) u32 = 1.6 MB (persistent)
constexpr size_t O_CNT   = 62400448;   // 1.6 MB
constexpr size_t O_SCO   = 65600448;
constexpr size_t O_AW    = 65800448;
constexpr size_t O_GEMB  = 66000448;
constexpr size_t O_STATS = 66033216;
constexpr size_t O_MISC  = 66035264;
constexpr size_t O_AGG   = 66035520;   // bf16 N*1024 = 102,400,000
constexpr size_t WS_NEED = 168435520;

extern "C" void kernel_launch(void* const* d_in, const int* in_sizes, int n_in,
                              void* d_out, int out_size, void* d_ws, size_t ws_size,
                              hipStream_t stream) {
  const void* x     = d_in[0];
  const void* ei    = d_in[1];
  const void* et    = d_in[2];
  const void* batch = d_in[3];
  const void* W1 = d_in[4],  *r1 = d_in[5],  *b1 = d_in[6];
  const void* W2 = d_in[7],  *r2 = d_in[8],  *b2 = d_in[9];
  const void* W3 = d_in[10], *r3 = d_in[11], *b3 = d_in[12];
  const void* g1 = d_in[13], *be1 = d_in[14];
  const void* g2 = d_in[15], *be2 = d_in[16];
  const void* A1 = d_in[17], *a1 = d_in[18];
  const void* A2 = d_in[19], *a2 = d_in[20];
  const void* C1 = d_in[21], *c1 = d_in[22];
  const void* C2 = d_in[23], *c2 = d_in[24];

  if (ws_size < WS_NEED){ k_wsfail<<<1, 1, 0, stream>>>((u32*)d_out); return; }
  char* ws = (char*)d_ws;
  float* out   = (float*)(ws + O_OUT);
  u16*   hbuf  = (u16*)(ws + O_H);
  u16*   xbf   = (u16*)(ws + O_XBF);
  u16*   wcat  = (u16*)(ws + O_WCAT);
  u16*   wext  = (u16*)(ws + O_WEXT);
  int*   ei_c  = (int*)(ws + O_EI);
  int*   et_c  = (int*)(ws + O_ET);
  int*   bat_c = (int*)(ws + O_BAT);
  u32*   src_s = (u32*)(ws + O_SRC);
  u32*   pairStart = (u32*)(ws + O_PST);
  u32*   cnt   = (u32*)(ws + O_CNT);
  float* sco   = (float*)(ws + O_SCO);
  float* aw    = (float*)(ws + O_AW);
  float* gemb  = (float*)(ws + O_GEMB);
  float* stats = (float*)(ws + O_STATS);
  u32*   misc  = (u32*)(ws + O_MISC);
  u16*   aggb  = (u16*)(ws + O_AGG);
  // pre-GEMM aliases inside the O_OUT region (out not yet live):
  u32* cursor    = (u32*)(ws + O_OUT);                 // 400K u32
  u32* blockSum  = (u32*)(ws + O_OUT + 1600000);       // 782 u32
  u32* blockBase = (u32*)(ws + O_OUT + 1604096);       // 782 u32
  u32* relOff = misc + 16;   // 16..24
  u32* smax = misc + 25;
  float* ssum = (float*)(misc + 26);
  u32* flags = misc + 27;
  u32* md = misc + 28;       // md[0]=fmode(f32?), md[1]=imode(int64?)

  hipMemsetAsync(ws + O_CNT, 0, 1600000, stream);
  hipMemsetAsync(ws + O_GEMB, 0, 32768 + 2048 + 256, stream);

  k_fdetect<<<1, 256, 0, stream>>>(x, md);
  k_idetect<<<1, 256, 0, stream>>>(et, md);
  k_icvt<<<6055, 256, 0, stream>>>(ei, et, batch, ei_c, et_c, bat_c, md);
  k_xcvt<<<6250, 256, 0, stream>>>(x, xbf, md, flags);
  k_wcat<<<1728, 256, 0, stream>>>(W1, r1, W2, r2, W3, r3, wcat, md, flags);
  k_wext<<<227, 256, 0, stream>>>(A1, a1, A2, a2, C1, c1, C2, c2, wext, md);

  k_count3<<<(EE + 255) / 256, 256, 0, stream>>>(ei_c, et_c, cnt);
  k_pairA<<<PAIR_B, 256, 0, stream>>>(cnt, blockSum);
  k_pairB<<<1, 64, 0, stream>>>(blockSum, blockBase);
  k_pairC<<<PAIR_B, 256, 0, stream>>>(cnt, blockBase, pairStart, cursor);
  k_reloff<<<1, 64, 0, stream>>>(pairStart, relOff);
  k_sort3<<<(EE + 255) / 256, 256, 0, stream>>>(ei_c, et_c, pairStart, cursor, src_s);

  const void* bias[3] = {b1, b2, b3};
  const void* gam[2] = {g1, g2};
  const void* bet[2] = {be1, be2};
  const u16* hin = xbf;
  for (int L = 0; L < 3; L++){
    const u16* wT = wcat + (size_t)L * 128 * 1152;
    k_agg<<<(NKEY + 3) / 4, 256, 0, stream>>>(hin, pairStart, src_s, aggb);
    k_gemm_big<<<391, 256, 0, stream>>>(hin, aggb, wT, bias[L], out, md);
    if (L < 2){
      k_bnstats<<<196, 256, 0, stream>>>(out, stats + L * 256);
      k_bnapply<<<6250, 256, 0, stream>>>(out, stats + L * 256, gam[L], bet[L], hbuf, md, flags, 4u << L);
      hin = hbuf;
    }
  }
  k_scores_mfma<<<391, 256, 0, stream>>>(out, wext, sco);
  k_max<<<128, 256, 0, stream>>>(sco, smax);
  k_expsum<<<128, 256, 0, stream>>>(sco, smax, aw, ssum, flags);
  k_pool<<<98, 128, 0, stream>>>(out, aw, ssum, bat_c, gemb, flags);
  k_final_mfma<<<391, 256, 0, stream>>>(out, gemb, bat_c, wext, d_out, md);
  k_diag<<<1, 64, 0, stream>>>(relOff, flags, md, d_out);
}

// Round 9
// 852.985 us; speedup vs baseline: 6.1657x; 1.1862x over previous
//
#include <hip/hip_runtime.h>
#include <hip/hip_bf16.h>

typedef unsigned int u32;
typedef unsigned short u16;
typedef __bf16 bf16_t;
typedef bf16_t bf16x8 __attribute__((ext_vector_type(8)));
typedef float f32x4 __attribute__((ext_vector_type(4)));

constexpr int NN = 50000;
constexpr int EE = 500000;
constexpr int RR = 8;
constexpr int NKEY = RR * NN;               // 400000
constexpr int PAIR_B = (NKEY + 511) / 512;  // 782

// wext element offsets (bf16 elems)
constexpr int WX_A1T = 0;       // [64][128]
constexpr int WX_C1T = 8192;    // [128][256]
constexpr int WX_C2T = 40960;   // [128][128]
constexpr int WX_A2  = 57344;   // [64]
constexpr int WX_a1  = 57408;   // [64]
constexpr int WX_c1  = 57472;   // [128]
constexpr int WX_c2  = 57600;   // [128]
constexpr int WX_a2s = 57728;   // [1]
constexpr int WX_TOT = 57729;

__device__ __forceinline__ float bf2f(u32 v){
  union { u32 u; float f; } x; x.u = (v & 0xFFFFu) << 16; return x.f;
}
__device__ __forceinline__ u16 f2bf(float f){
  union { u32 u; float f; } x; x.f = f;
  u32 r = x.u + 0x7FFFu + ((x.u >> 16) & 1u);
  return (u16)(r >> 16);
}
__device__ __forceinline__ float lrelu(float x){ return x > 0.f ? x : 0.1f * x; }
__device__ __forceinline__ float ldf(const void* p, int i, u32 fm){
  return fm ? ((const float*)p)[i] : bf2f(((const u16*)p)[i]);
}

// ---------------- dtype detectors ----------------
__global__ void k_fdetect(const void* x, u32* md){
  __shared__ u32 c;
  if (threadIdx.x == 0) c = 0;
  __syncthreads();
  const u16* p = (const u16*)x;
  u32 loc = 0;
  for (int j = 0; j < 16; j++){
    u16 v = p[threadIdx.x * 16 + j];
    u32 e = (v >> 7) & 0xFF;
    if (e >= 0xFD) loc++;
  }
  atomicAdd(&c, loc);
  __syncthreads();
  if (threadIdx.x == 0) md[0] = (c >= 4) ? 1u : 0u;
}
__global__ void k_idetect(const void* et, u32* md){
  __shared__ u32 c;
  if (threadIdx.x == 0) c = 0;
  __syncthreads();
  const int* p = (const int*)et;
  u32 loc = 0;
  for (int j = 0; j < 8; j++){
    int idx = 2 * (threadIdx.x * 8 + j) + 1;
    if (p[idx] != 0) loc++;
  }
  atomicAdd(&c, loc);
  __syncthreads();
  if (threadIdx.x == 0) md[1] = (c == 0) ? 1u : 0u;
}

// ---------------- int conversion -> int32 ws copies
__global__ void k_icvt(const void* ei, const void* et, const void* bat,
                       int* ei_c, int* et_c, int* bat_c, const u32* md){
  u32 im = md[1];
  int i = blockIdx.x * 256 + threadIdx.x;
  if (i < 2 * EE){
    const int* p = (const int*)ei;
    ei_c[i] = im ? p[2 * i] : p[i];
  } else if (i < 3 * EE){
    int j = i - 2 * EE;
    const int* p = (const int*)et;
    et_c[j] = im ? p[2 * j] : p[j];
  } else if (i < 3 * EE + NN){
    int j = i - 3 * EE;
    const int* p = (const int*)bat;
    bat_c[j] = im ? p[2 * j] : p[j];
  }
}

// ---------------- x conversion -> bf16 ws copy (+NaN flag bit1)
__global__ void k_xcvt(const void* x, u16* xb, const u32* md, u32* flags){
  u32 fm = md[0];
  int i4 = (blockIdx.x * 256 + threadIdx.x) * 4;
  if (i4 >= NN * 128) return;
  float v[4];
  if (fm){
    float4 f = *(const float4*)((const float*)x + i4);
    v[0]=f.x; v[1]=f.y; v[2]=f.z; v[3]=f.w;
  } else {
    uint2 u = *(const uint2*)((const u16*)x + i4);
    v[0]=bf2f(u.x); v[1]=bf2f(u.x>>16); v[2]=bf2f(u.y); v[3]=bf2f(u.y>>16);
  }
  bool bad = false;
  u16 o[4];
  for (int j = 0; j < 4; j++){
    if (v[j] != v[j]){ bad = true; v[j] = 0.f; }
    o[j] = f2bf(v[j]);
  }
  unsigned long long bal = __ballot(bad);
  if (bal && (threadIdx.x & 63) == 0) atomicOr(flags, 2u);
  uint2 st;
  st.x = (u32)o[0] | ((u32)o[1] << 16);
  st.y = (u32)o[2] | ((u32)o[3] << 16);
  *(uint2*)(xb + i4) = st;
}

// ---------------- weight transpose: wcatT[L][n][k]; k<1024 -> W[L][k][n], else root[k-1024][n]
__global__ void k_wcat(const void* W1, const void* r1, const void* W2, const void* r2,
                       const void* W3, const void* r3, u16* wcatT, const u32* md, u32* flags){
  u32 fm = md[0];
  int idx = blockIdx.x * 256 + threadIdx.x;
  if (idx >= 3 * 128 * 1152) return;
  int L = idx / (128 * 1152);
  int rem = idx % (128 * 1152);
  int n = rem / 1152, k = rem % 1152;
  const void* W  = (L == 0) ? W1 : ((L == 1) ? W2 : W3);
  const void* rt = (L == 0) ? r1 : ((L == 1) ? r2 : r3);
  float v = (k < 1024) ? ldf(W, k * 128 + n, fm) : ldf(rt, (k - 1024) * 128 + n, fm);
  if (v != v){ v = 0.f; atomicOr(flags, 2u); }
  wcatT[idx] = f2bf(v);
}

// ---------------- small-MLP weight prep
__global__ void k_wext(const void* A1, const void* a1, const void* A2, const void* a2,
                       const void* C1, const void* c1, const void* C2, const void* c2,
                       u16* wext, const u32* md){
  u32 fm = md[0];
  int idx = blockIdx.x * 256 + threadIdx.x;
  if (idx >= WX_TOT) return;
  float v;
  if (idx < WX_C1T){
    int n = idx >> 7, k = idx & 127;
    v = ldf(A1, k * 64 + n, fm);
  } else if (idx < WX_C2T){
    int j = idx - WX_C1T; int n = j >> 8, k = j & 255;
    v = ldf(C1, k * 128 + n, fm);
  } else if (idx < WX_A2){
    int j = idx - WX_C2T; int n = j >> 7, k = j & 127;
    v = ldf(C2, k * 128 + n, fm);
  } else if (idx < WX_a1){ v = ldf(A2, idx - WX_A2, fm); }
  else if (idx < WX_c1){ v = ldf(a1, idx - WX_a1, fm); }
  else if (idx < WX_c2){ v = ldf(c1, idx - WX_c1, fm); }
  else if (idx < WX_a2s){ v = ldf(c2, idx - WX_c2, fm); }
  else { v = ldf(a2, 0, fm); }
  wext[idx] = f2bf(v);
}

// ---------------- (rel,dst) counting sort ----------------
__global__ void k_count3(const int* __restrict__ ei, const int* __restrict__ et, u32* __restrict__ cnt){
  int e = blockIdx.x * 256 + threadIdx.x;
  if (e >= EE) return;
  atomicAdd(&cnt[ei[EE + e] * RR + et[e]], 1u);
}
__global__ void k_pairA(const u32* __restrict__ cnt, u32* __restrict__ blockSum){
  __shared__ u32 sd[256];
  int b = blockIdx.x, t = threadIdx.x;
  u32 s = 0;
  for (int j = 0; j < 2; j++){
    int key = b * 512 + t * 2 + j;
    if (key < NKEY){ int r = key / NN, d = key % NN; s += cnt[d * RR + r]; }
  }
  sd[t] = s; __syncthreads();
  for (int off = 128; off; off >>= 1){ if (t < off) sd[t] += sd[t + off]; __syncthreads(); }
  if (t == 0) blockSum[b] = sd[0];
}
__global__ void k_pairB(const u32* __restrict__ blockSum, u32* __restrict__ blockBase){
  int lane = threadIdx.x;   // 64
  u32 loc[13]; u32 s = 0;
  for (int j = 0; j < 13; j++){
    int b = lane * 13 + j;
    u32 v = (b < PAIR_B) ? blockSum[b] : 0u;
    loc[j] = s; s += v;
  }
  u32 tot = s;
  for (int off = 1; off < 64; off <<= 1){
    u32 x = __shfl_up(tot, off);
    if (lane >= off) tot += x;
  }
  u32 excl = tot - s;
  for (int j = 0; j < 13; j++){
    int b = lane * 13 + j;
    if (b < PAIR_B) blockBase[b] = excl + loc[j];
  }
}
__global__ void k_pairC(const u32* __restrict__ cnt, const u32* __restrict__ blockBase,
                        u32* __restrict__ pairStart, u32* __restrict__ cursor){
  __shared__ u32 sd[256];
  int b = blockIdx.x, t = threadIdx.x;
  int k0 = b * 512 + t * 2;
  u32 v0 = 0, v1 = 0;
  if (k0 < NKEY){ int r = k0 / NN, d = k0 % NN; v0 = cnt[d * RR + r]; }
  if (k0 + 1 < NKEY){ int r = (k0 + 1) / NN, d = (k0 + 1) % NN; v1 = cnt[d * RR + r]; }
  sd[t] = v0 + v1; __syncthreads();
  for (int off = 1; off < 256; off <<= 1){
    u32 x = (t >= off) ? sd[t - off] : 0u;
    __syncthreads();
    sd[t] += x;
    __syncthreads();
  }
  u32 excl = sd[t] - (v0 + v1);
  u32 base = blockBase[b] + excl;
  if (k0 < NKEY){ pairStart[k0] = base; cursor[k0] = 0u; }
  if (k0 + 1 < NKEY){ pairStart[k0 + 1] = base + v0; cursor[k0 + 1] = 0u; }
}
__global__ void k_reloff(u32* __restrict__ pairStart, u32* __restrict__ relOff){
  int t = threadIdx.x;
  if (t < RR) relOff[t] = pairStart[t * NN];
  if (t == RR){ relOff[RR] = (u32)EE; pairStart[NKEY] = (u32)EE; }
}
__global__ void k_sort3(const int* __restrict__ ei, const int* __restrict__ et,
                        const u32* __restrict__ pairStart, u32* __restrict__ cursor,
                        u32* __restrict__ src_s){
  int e = blockIdx.x * 256 + threadIdx.x;
  if (e >= EE) return;
  int r = et[e], d = ei[EE + e];
  u32 key = (u32)r * NN + (u32)d;
  u32 p = pairStart[key] + atomicAdd(&cursor[key], 1u);
  src_s[p] = (u32)ei[e];
}

// ---------------- segment-sum aggregation: agg[d][r*128..] = mean h[src] over key segment
__global__ __launch_bounds__(256) void k_agg(const u16* __restrict__ h,
                                             const u32* __restrict__ pairStart,
                                             const u32* __restrict__ src_s,
                                             u16* __restrict__ agg){
  int wid = blockIdx.x * 4 + (threadIdx.x >> 6);
  if (wid >= NKEY) return;
  int lane = threadIdx.x & 63;
  u32 s = pairStart[wid], e = pairStart[wid + 1];
  int r = wid / NN, d = wid - r * NN;
  float a0 = 0.f, a1 = 0.f;
  for (u32 j = s; j < e; j++){
    u32 src = src_s[j];
    u32 v = *(const u32*)(h + (size_t)src * 128 + lane * 2);
    a0 += bf2f(v); a1 += bf2f(v >> 16);
  }
  int c = (int)(e - s);
  float sc = 1.0f / (float)max(c, 1);
  u32 st = (u32)f2bf(a0 * sc) | ((u32)f2bf(a1 * sc) << 16);
  *(u32*)(agg + (size_t)d * 1024 + r * 128 + lane * 2) = st;
}

// ---------------- big GEMM: out[N,128] = [agg | h] (K=1152) @ wcatT + bias
#define PADE 8
__global__ __launch_bounds__(256) void k_gemm_big(const u16* __restrict__ h,
                                                  const u16* __restrict__ agg,
                                                  const u16* __restrict__ wT,
                                                  const void* __restrict__ bias,
                                                  float* __restrict__ out, const u32* md){
  __shared__ u16 As[128][64 + PADE];
  __shared__ u16 Bs[128][64 + PADE];
  u32 fm = md[0];
  int m0 = blockIdx.x * 128;
  int tid = threadIdx.x;
  int w = tid >> 6, lane = tid & 63, qd = lane >> 4, l16 = lane & 15;
  f32x4 acc[2][8];
  for (int i = 0; i < 2; i++) for (int j = 0; j < 8; j++) acc[i][j] = (f32x4){0.f,0.f,0.f,0.f};
  for (int k0 = 0; k0 < 1152; k0 += 64){
    __syncthreads();
    for (int it = 0; it < 4; it++){
      int lin = it * 2048 + tid * 8;
      int row = lin >> 6, kl = lin & 63;
      int node = m0 + row;
      int k = k0 + kl;
      uint4 v = make_uint4(0u,0u,0u,0u);
      if (node < NN){
        if (k < 1024) v = *(const uint4*)(agg + (size_t)node * 1024 + k);
        else v = *(const uint4*)(h + (size_t)node * 128 + (k - 1024));
      }
      *(uint4*)(&As[row][kl]) = v;
      uint4 b = *(const uint4*)(wT + (size_t)row * 1152 + k0 + kl);
      *(uint4*)(&Bs[row][kl]) = b;
    }
    __syncthreads();
    for (int kk = 0; kk < 64; kk += 32){
      bf16x8 a[2], bf[8];
      for (int rt = 0; rt < 2; rt++) a[rt] = *(const bf16x8*)(&As[w * 32 + rt * 16 + l16][kk + qd * 8]);
      for (int ct = 0; ct < 8; ct++) bf[ct] = *(const bf16x8*)(&Bs[ct * 16 + l16][kk + qd * 8]);
      for (int rt = 0; rt < 2; rt++)
        for (int ct = 0; ct < 8; ct++)
          acc[rt][ct] = __builtin_amdgcn_mfma_f32_16x16x32_bf16(a[rt], bf[ct], acc[rt][ct], 0, 0, 0);
    }
  }
  for (int rt = 0; rt < 2; rt++){
    int rbase = m0 + w * 32 + rt * 16 + qd * 4;
    for (int ct = 0; ct < 8; ct++){
      int col = ct * 16 + l16;
      float bv = ldf(bias, col, fm);
      for (int rg = 0; rg < 4; rg++){
        int node = rbase + rg;
        if (node < NN) out[node * 128 + col] = acc[rt][ct][rg] + bv;
      }
    }
  }
}

// ---------------- BatchNorm (391 blocks × 128 rows)
__global__ void k_bnstats(const float* __restrict__ out, float* __restrict__ stats){
  __shared__ float sb[256], sb2[256];
  int tid = threadIdx.x;
  int col = tid & 127, half = tid >> 7;
  int r0 = blockIdx.x * 128;
  float s = 0.f, s2 = 0.f;
  for (int i = half; i < 128; i += 2){
    int n = r0 + i;
    if (n < NN){ float v = out[n * 128 + col]; s += v; s2 += v * v; }
  }
  sb[tid] = s; sb2[tid] = s2;
  __syncthreads();
  if (half == 0){
    unsafeAtomicAdd(&stats[col],       sb[col] + sb[col + 128]);
    unsafeAtomicAdd(&stats[128 + col], sb2[col] + sb2[col + 128]);
  }
}

__global__ void k_bnapply(const float* __restrict__ out, const float* __restrict__ stats,
                          const void* __restrict__ g, const void* __restrict__ beta,
                          u16* __restrict__ hout, const u32* md, u32* flags, u32 layerbit){
  u32 fm = md[0];
  int idx = (blockIdx.x * 256 + threadIdx.x) * 4;
  if (idx >= NN * 128) return;
  int col = idx & 127;
  float4 v = *(const float4*)(out + idx);
  float vv[4] = {v.x, v.y, v.z, v.w};
  bool bad = false;
  u16 o[4];
  for (int j = 0; j < 4; j++){
    int c = col + j;
    float mu = stats[c] * (1.0f / NN);
    float var = fmaxf(stats[128 + c] * (1.0f / NN) - mu * mu, 0.f);
    float sc = ldf(g, c, fm) * rsqrtf(var + 1e-5f);
    float sh = ldf(beta, c, fm) - mu * sc;
    float r = vv[j] * sc + sh;
    if (r != r || sc != sc){ bad = true; r = 0.f; }
    o[j] = f2bf(lrelu(r));
  }
  unsigned long long bal = __ballot(bad);
  if (bal && (threadIdx.x & 63) == 0) atomicOr(flags, layerbit);
  uint2 st;
  st.x = (u32)o[0] | ((u32)o[1] << 16);
  st.y = (u32)o[2] | ((u32)o[3] << 16);
  *(uint2*)(hout + idx) = st;
}

// ---------------- attention scores via MFMA
__global__ __launch_bounds__(256) void k_scores_mfma(const float* __restrict__ emb,
                                                     const u16* __restrict__ wext,
                                                     float* __restrict__ scores){
  __shared__ u16 As[128][136];
  int m0 = blockIdx.x * 128;
  int tid = threadIdx.x;
  int w = tid >> 6, lane = tid & 63, qd = lane >> 4, l16 = lane & 15;
  for (int it = 0; it < 16; it++){
    int lin = it * 1024 + tid * 4;
    int row = lin >> 7, c = lin & 127;
    int node = m0 + row;
    float4 v = make_float4(0.f,0.f,0.f,0.f);
    if (node < NN) v = *(const float4*)(emb + (size_t)node * 128 + c);
    uint2 st;
    st.x = (u32)f2bf(v.x) | ((u32)f2bf(v.y) << 16);
    st.y = (u32)f2bf(v.z) | ((u32)f2bf(v.w) << 16);
    *(uint2*)(&As[row][c]) = st;
  }
  __syncthreads();
  f32x4 acc[2][4];
  for (int i = 0; i < 2; i++) for (int j = 0; j < 4; j++) acc[i][j] = (f32x4){0.f,0.f,0.f,0.f};
  for (int k0 = 0; k0 < 4; k0++){
    bf16x8 a[2];
    a[0] = *(const bf16x8*)(&As[(w * 2) * 16 + l16][k0 * 32 + qd * 8]);
    a[1] = *(const bf16x8*)(&As[(w * 2 + 1) * 16 + l16][k0 * 32 + qd * 8]);
    for (int ct = 0; ct < 4; ct++){
      bf16x8 b = *(const bf16x8*)(wext + WX_A1T + (size_t)(ct * 16 + l16) * 128 + k0 * 32 + qd * 8);
      acc[0][ct] = __builtin_amdgcn_mfma_f32_16x16x32_bf16(a[0], b, acc[0][ct], 0, 0, 0);
      acc[1][ct] = __builtin_amdgcn_mfma_f32_16x16x32_bf16(a[1], b, acc[1][ct], 0, 0, 0);
    }
  }
  float a1v[4], a2v[4];
  for (int ct = 0; ct < 4; ct++){
    a1v[ct] = bf2f(wext[WX_a1 + ct * 16 + l16]);
    a2v[ct] = bf2f(wext[WX_A2 + ct * 16 + l16]);
  }
  float a2s = bf2f(wext[WX_a2s]);
  for (int rt = 0; rt < 2; rt++)
    for (int rg = 0; rg < 4; rg++){
      float s = 0.f;
      for (int ct = 0; ct < 4; ct++)
        s += lrelu(acc[rt][ct][rg] + a1v[ct]) * a2v[ct];
      s += __shfl_xor(s, 1); s += __shfl_xor(s, 2);
      s += __shfl_xor(s, 4); s += __shfl_xor(s, 8);
      int row = m0 + (w * 2 + rt) * 16 + qd * 4 + rg;
      if (l16 == 0 && row < NN) scores[row] = s + a2s;
    }
}

__device__ __forceinline__ u32 fmap(float f){
  union{u32 u; float f;} x; x.f = f;
  return (x.u & 0x80000000u) ? ~x.u : (x.u | 0x80000000u);
}
__device__ __forceinline__ float funmap(u32 m){
  union{u32 u; float f;} x;
  x.u = (m & 0x80000000u) ? (m ^ 0x80000000u) : ~m;
  return x.f;
}

__global__ void k_max(const float* __restrict__ scores, u32* smax){
  int gid = blockIdx.x * 256 + threadIdx.x;
  float m = -1e30f;
  for (int i = gid; i < NN; i += 256 * 128) m = fmaxf(m, scores[i]);
  for (int off = 32; off; off >>= 1) m = fmaxf(m, __shfl_down(m, off));
  if ((threadIdx.x & 63) == 0) atomicMax(smax, fmap(m));
}

__global__ void k_expsum(const float* __restrict__ scores, const u32* smax,
                         float* __restrict__ attnw, float* ssum, u32* flags){
  float mx = funmap(*smax);
  int gid = blockIdx.x * 256 + threadIdx.x;
  if (mx != mx){ if (gid == 0) atomicOr(flags, 32u); mx = 0.f; }
  float s = 0.f;
  bool bad = false;
  for (int i = gid; i < NN; i += 256 * 128){
    float e = __expf(scores[i] - mx);
    if (e != e){ bad = true; e = 0.f; }
    attnw[i] = e; s += e;
  }
  unsigned long long bal = __ballot(bad);
  if (bal && (threadIdx.x & 63) == 0) atomicOr(flags, 32u);
  for (int off = 32; off; off >>= 1) s += __shfl_down(s, off);
  if ((threadIdx.x & 63) == 0) unsafeAtomicAdd(ssum, s);
}

// ---------------- pooling: 32 nodes/block, per-run atomics (1563 blocks)
constexpr int POOL_CHUNK = 32;
__global__ __launch_bounds__(128) void k_pool(const float* __restrict__ emb,
                                              const float* __restrict__ attnw,
                                              const float* __restrict__ ssum,
                                              const int* __restrict__ batch,
                                              float* __restrict__ gemb, u32* flags){
  int t = threadIdx.x;
  int n0 = blockIdx.x * POOL_CHUNK;
  if (n0 >= NN) return;
  int n1 = min(n0 + POOL_CHUNK, NN);
  float sv = *ssum;
  bool bad = !(sv > 0.f) || (sv != sv);
  if (bad && t == 0 && blockIdx.x == 0) atomicOr(flags, 64u);
  float rs = bad ? 0.f : 1.0f / sv;
  int cur = batch[n0];
  float acc = 0.f;
  for (int n = n0; n < n1; n++){
    int b = batch[n];
    if (b != cur){ unsafeAtomicAdd(&gemb[cur * 128 + t], acc * rs); acc = 0.f; cur = b; }
    acc += emb[(size_t)n * 128 + t] * attnw[n];
  }
  unsafeAtomicAdd(&gemb[cur * 128 + t], acc * rs);
}

// ---------------- final combiner via MFMA + row L2 normalize
__global__ __launch_bounds__(256) void k_final_mfma(const float* __restrict__ emb,
                                                    const float* __restrict__ gemb,
                                                    const int* __restrict__ batch,
                                                    const u16* __restrict__ wext,
                                                    void* __restrict__ outp,
                                                    const u32* md){
  __shared__ u16 As[128][264];
  u16 (*Hs)[136] = (u16(*)[136])(&As[0][0]);
  u32 fm = md[0];
  int m0 = blockIdx.x * 128;
  int tid = threadIdx.x;
  int w = tid >> 6, lane = tid & 63, qd = lane >> 4, l16 = lane & 15;
  for (int it = 0; it < 32; it++){
    int lin = it * 1024 + tid * 4;
    int row = lin >> 8, c = lin & 255;
    int node = m0 + row;
    float4 v = make_float4(0.f,0.f,0.f,0.f);
    if (node < NN){
      if (c < 128) v = *(const float4*)(emb + (size_t)node * 128 + c);
      else { int g = batch[node]; v = *(const float4*)(gemb + (size_t)g * 128 + (c - 128)); }
    }
    uint2 st;
    st.x = (u32)f2bf(v.x) | ((u32)f2bf(v.y) << 16);
    st.y = (u32)f2bf(v.z) | ((u32)f2bf(v.w) << 16);
    *(uint2*)(&As[row][c]) = st;
  }
  __syncthreads();
  f32x4 acc[2][8];
  for (int i = 0; i < 2; i++) for (int j = 0; j < 8; j++) acc[i][j] = (f32x4){0.f,0.f,0.f,0.f};
  for (int k0 = 0; k0 < 8; k0++){
    bf16x8 a[2];
    a[0] = *(const bf16x8*)(&As[(w * 2) * 16 + l16][k0 * 32 + qd * 8]);
    a[1] = *(const bf16x8*)(&As[(w * 2 + 1) * 16 + l16][k0 * 32 + qd * 8]);
    for (int ct = 0; ct < 8; ct++){
      bf16x8 b = *(const bf16x8*)(wext + WX_C1T + (size_t)(ct * 16 + l16) * 256 + k0 * 32 + qd * 8);
      acc[0][ct] = __builtin_amdgcn_mfma_f32_16x16x32_bf16(a[0], b, acc[0][ct], 0, 0, 0);
      acc[1][ct] = __builtin_amdgcn_mfma_f32_16x16x32_bf16(a[1], b, acc[1][ct], 0, 0, 0);
    }
  }
  __syncthreads();
  for (int rt = 0; rt < 2; rt++)
    for (int ct = 0; ct < 8; ct++){
      float c1v = bf2f(wext[WX_c1 + ct * 16 + l16]);
      for (int rg = 0; rg < 4; rg++){
        int row = (w * 2 + rt) * 16 + qd * 4 + rg;
        Hs[row][ct * 16 + l16] = f2bf(lrelu(acc[rt][ct][rg] + c1v));
      }
    }
  __syncthreads();
  f32x4 acc2[2][8];
  for (int i = 0; i < 2; i++) for (int j = 0; j < 8; j++) acc2[i][j] = (f32x4){0.f,0.f,0.f,0.f};
  for (int k0 = 0; k0 < 4; k0++){
    bf16x8 a[2];
    a[0] = *(const bf16x8*)(&Hs[(w * 2) * 16 + l16][k0 * 32 + qd * 8]);
    a[1] = *(const bf16x8*)(&Hs[(w * 2 + 1) * 16 + l16][k0 * 32 + qd * 8]);
    for (int ct = 0; ct < 8; ct++){
      bf16x8 b = *(const bf16x8*)(wext + WX_C2T + (size_t)(ct * 16 + l16) * 128 + k0 * 32 + qd * 8);
      acc2[0][ct] = __builtin_amdgcn_mfma_f32_16x16x32_bf16(a[0], b, acc2[0][ct], 0, 0, 0);
      acc2[1][ct] = __builtin_amdgcn_mfma_f32_16x16x32_bf16(a[1], b, acc2[1][ct], 0, 0, 0);
    }
  }
  float c2v[8];
  for (int ct = 0; ct < 8; ct++) c2v[ct] = bf2f(wext[WX_c2 + ct * 16 + l16]);
  for (int rt = 0; rt < 2; rt++)
    for (int rg = 0; rg < 4; rg++){
      float ss = 0.f;
      for (int ct = 0; ct < 8; ct++){
        float o = acc2[rt][ct][rg] + c2v[ct];
        ss += o * o;
      }
      ss += __shfl_xor(ss, 1); ss += __shfl_xor(ss, 2);
      ss += __shfl_xor(ss, 4); ss += __shfl_xor(ss, 8);
      float sc = 1.0f / fmaxf(sqrtf(ss), 1e-12f);
      int row = m0 + (w * 2 + rt) * 16 + qd * 4 + rg;
      if (row < NN){
        if (fm){
          float* op = (float*)outp;
          for (int ct = 0; ct < 8; ct++)
            op[(size_t)row * 128 + ct * 16 + l16] = (acc2[rt][ct][rg] + c2v[ct]) * sc;
        } else {
          u16* op = (u16*)outp;
          for (int ct = 0; ct < 8; ct++)
            op[(size_t)row * 128 + ct * 16 + l16] = f2bf((acc2[rt][ct][rg] + c2v[ct]) * sc);
        }
      }
    }
}

// ---------------- diag sentinels
__global__ void k_diag(const u32* relOff, const u32* flags, const u32* md, void* outp){
  if (threadIdx.x != 0 || blockIdx.x != 0) return;
  u32 fm = md[0];
  u32 f = flags[0];
  if (relOff[RR] != (u32)EE) f |= 1u;
  for (int b = 0; b < 9; b++){
    if (f & (1u << b)){
      float s = (float)(131072 >> b);
      if (fm) ((float*)outp)[b] = s;
      else ((u16*)outp)[b] = f2bf(s);
    }
  }
}
__global__ void k_wsfail(u32* outp){ outp[0] = 0x43000000u; }

// ---------------- workspace layout (bytes)
constexpr size_t O_OUT   = 0;          // f32 N*128; pre-GEMM aliases: cursor/blockSum/blockBase
constexpr size_t O_H     = 25600000;
constexpr size_t O_XBF   = 38400000;
constexpr size_t O_WCAT  = 51200000;
constexpr size_t O_WEXT  = 52084736;
constexpr size_t O_EI    = 52200448;
constexpr size_t O_ET    = 56200448;
constexpr size_t O_BAT   = 58200448;
constexpr size_t O_SRC   = 58400448;   // 2 MB (src_s)
constexpr size_t O_PST   = 60400448;   // pairStart: (NKEY+1) u32
constexpr size_t O_CNT   = 62400448;   // 1.6 MB
constexpr size_t O_SCO   = 65600448;
constexpr size_t O_AW    = 65800448;
constexpr size_t O_GEMB  = 66000448;
constexpr size_t O_STATS = 66033216;
constexpr size_t O_MISC  = 66035264;
constexpr size_t O_AGG   = 66035520;   // bf16 N*1024 = 102,400,000
constexpr size_t WS_NEED = 168435520;

extern "C" void kernel_launch(void* const* d_in, const int* in_sizes, int n_in,
                              void* d_out, int out_size, void* d_ws, size_t ws_size,
                              hipStream_t stream) {
  const void* x     = d_in[0];
  const void* ei    = d_in[1];
  const void* et    = d_in[2];
  const void* batch = d_in[3];
  const void* W1 = d_in[4],  *r1 = d_in[5],  *b1 = d_in[6];
  const void* W2 = d_in[7],  *r2 = d_in[8],  *b2 = d_in[9];
  const void* W3 = d_in[10], *r3 = d_in[11], *b3 = d_in[12];
  const void* g1 = d_in[13], *be1 = d_in[14];
  const void* g2 = d_in[15], *be2 = d_in[16];
  const void* A1 = d_in[17], *a1 = d_in[18];
  const void* A2 = d_in[19], *a2 = d_in[20];
  const void* C1 = d_in[21], *c1 = d_in[22];
  const void* C2 = d_in[23], *c2 = d_in[24];

  if (ws_size < WS_NEED){ k_wsfail<<<1, 1, 0, stream>>>((u32*)d_out); return; }
  char* ws = (char*)d_ws;
  float* out   = (float*)(ws + O_OUT);
  u16*   hbuf  = (u16*)(ws + O_H);
  u16*   xbf   = (u16*)(ws + O_XBF);
  u16*   wcat  = (u16*)(ws + O_WCAT);
  u16*   wext  = (u16*)(ws + O_WEXT);
  int*   ei_c  = (int*)(ws + O_EI);
  int*   et_c  = (int*)(ws + O_ET);
  int*   bat_c = (int*)(ws + O_BAT);
  u32*   src_s = (u32*)(ws + O_SRC);
  u32*   pairStart = (u32*)(ws + O_PST);
  u32*   cnt   = (u32*)(ws + O_CNT);
  float* sco   = (float*)(ws + O_SCO);
  float* aw    = (float*)(ws + O_AW);
  float* gemb  = (float*)(ws + O_GEMB);
  float* stats = (float*)(ws + O_STATS);
  u32*   misc  = (u32*)(ws + O_MISC);
  u16*   aggb  = (u16*)(ws + O_AGG);
  u32* cursor    = (u32*)(ws + O_OUT);
  u32* blockSum  = (u32*)(ws + O_OUT + 1600000);
  u32* blockBase = (u32*)(ws + O_OUT + 1604096);
  u32* relOff = misc + 16;
  u32* smax = misc + 25;
  float* ssum = (float*)(misc + 26);
  u32* flags = misc + 27;
  u32* md = misc + 28;

  hipMemsetAsync(ws + O_CNT, 0, 1600000, stream);
  hipMemsetAsync(ws + O_GEMB, 0, 32768 + 2048 + 256, stream);

  k_fdetect<<<1, 256, 0, stream>>>(x, md);
  k_idetect<<<1, 256, 0, stream>>>(et, md);
  k_icvt<<<6055, 256, 0, stream>>>(ei, et, batch, ei_c, et_c, bat_c, md);
  k_xcvt<<<6250, 256, 0, stream>>>(x, xbf, md, flags);
  k_wcat<<<1728, 256, 0, stream>>>(W1, r1, W2, r2, W3, r3, wcat, md, flags);
  k_wext<<<227, 256, 0, stream>>>(A1, a1, A2, a2, C1, c1, C2, c2, wext, md);

  k_count3<<<(EE + 255) / 256, 256, 0, stream>>>(ei_c, et_c, cnt);
  k_pairA<<<PAIR_B, 256, 0, stream>>>(cnt, blockSum);
  k_pairB<<<1, 64, 0, stream>>>(blockSum, blockBase);
  k_pairC<<<PAIR_B, 256, 0, stream>>>(cnt, blockBase, pairStart, cursor);
  k_reloff<<<1, 64, 0, stream>>>(pairStart, relOff);
  k_sort3<<<(EE + 255) / 256, 256, 0, stream>>>(ei_c, et_c, pairStart, cursor, src_s);

  const void* bias[3] = {b1, b2, b3};
  const void* gam[2] = {g1, g2};
  const void* bet[2] = {be1, be2};
  const u16* hin = xbf;
  for (int L = 0; L < 3; L++){
    const u16* wT = wcat + (size_t)L * 128 * 1152;
    k_agg<<<(NKEY + 3) / 4, 256, 0, stream>>>(hin, pairStart, src_s, aggb);
    k_gemm_big<<<391, 256, 0, stream>>>(hin, aggb, wT, bias[L], out, md);
    if (L < 2){
      k_bnstats<<<391, 256, 0, stream>>>(out, stats + L * 256);
      k_bnapply<<<6250, 256, 0, stream>>>(out, stats + L * 256, gam[L], bet[L], hbuf, md, flags, 4u << L);
      hin = hbuf;
    }
  }
  k_scores_mfma<<<391, 256, 0, stream>>>(out, wext, sco);
  k_max<<<128, 256, 0, stream>>>(sco, smax);
  k_expsum<<<128, 256, 0, stream>>>(sco, smax, aw, ssum, flags);
  k_pool<<<(NN + POOL_CHUNK - 1) / POOL_CHUNK, 128, 0, stream>>>(out, aw, ssum, bat_c, gemb, flags);
  k_final_mfma<<<391, 256, 0, stream>>>(out, gemb, bat_c, wext, d_out, md);
  k_diag<<<1, 64, 0, stream>>>(relOff, flags, md, d_out);
}